// Round 11
// baseline (1175.570 us; speedup 1.0000x reference)
//
#include <hip/hip_runtime.h>
#include <hip/hip_bf16.h>
#include <math.h>

#define BB 64
#define SS 512
#define HH 64
#define DD 128
#define NHD 8
#define ROWS (BB*SS)   // 32768

typedef unsigned short u16;
typedef __attribute__((ext_vector_type(8))) short bf16x8;
typedef __attribute__((ext_vector_type(4))) float f32x4;

__device__ __forceinline__ u16 f2b(float f) {
  union { float f; unsigned u; } x; x.f = f;
  unsigned r = x.u + 0x7fffu + ((x.u >> 16) & 1u);
  return (u16)(r >> 16);
}

__device__ __forceinline__ float b2f(u16 u) {
  return __uint_as_float(((unsigned)u) << 16);
}

// packed bf16 convert (RNE), 1 instruction for 2 values.
__device__ __forceinline__ unsigned cvt_pk_bf16(float lo, float hi) {
  unsigned r;
  asm("v_cvt_pk_bf16_f32 %0, %1, %2" : "=v"(r) : "v"(lo), "v"(hi));
  return r;
}

__device__ __forceinline__ float fast_tanh(float x) {
  float ax = fminf(fabsf(x), 15.f);
  float e = __expf(2.f * ax);
  float r = 1.f - __fdividef(2.f, e + 1.f);
  return copysignf(r, x);
}

__device__ __forceinline__ void barrier_lds() {
  __builtin_amdgcn_s_waitcnt(0xC07F);   // lgkmcnt(0) only
  __builtin_amdgcn_s_barrier();
}

__device__ __forceinline__ void wait_lds() {
  __builtin_amdgcn_s_waitcnt(0xC07F);   // lgkmcnt(0), intra-wave LDS RAW
}

// pair-combine via DPP (VALU, not LDS pipe): add value of lane^1
__device__ __forceinline__ float dpp_xor1_add(float x) {
  int pi = __float_as_int(x);
  int po = __builtin_amdgcn_update_dpp(0, pi, 0xB1 /*quad_perm [1,0,3,2]*/,
                                       0xF, 0xF, true);
  return x + __int_as_float(po);
}

template <int CTRL>
__device__ __forceinline__ float dpp_add(float x) {
  int po = __builtin_amdgcn_update_dpp(0, __float_as_int(x), CTRL, 0xF, 0xF, true);
  return x + __int_as_float(po);
}
// sum across each 16-lane group, all on the VALU pipe
__device__ __forceinline__ float red16(float x) {
  x = dpp_add<0xB1>(x);    // quad_perm xor1
  x = dpp_add<0x4E>(x);    // quad_perm xor2
  x = dpp_add<0x141>(x);   // row_half_mirror (combines 4-groups)
  x = dpp_add<0x140>(x);   // row_mirror (combines 8-halves)
  return x;
}

// ---------------------------------------------------------------------------
// SDE scan v10 (verified 577 us): 8 waves (0-3 drift, 4-7 diffusion), ONE
// barrier per step, K-segmented stage B, redundant reduce + LDS-staged
// stage C per wave, per-wave private y. Stable local optimum — frozen.
// ---------------------------------------------------------------------------
__global__ __attribute__((amdgpu_flat_work_group_size(512, 512)))
__attribute__((amdgpu_waves_per_eu(2, 2))) void sde_kernel(
    const float* __restrict__ ts, const float* __restrict__ noise,
    const float* __restrict__ dW1, const float* __restrict__ db1,
    const float* __restrict__ dW2, const float* __restrict__ db2,
    const float* __restrict__ dW3, const float* __restrict__ db3,
    const float* __restrict__ gW1, const float* __restrict__ gb1,
    const float* __restrict__ gW2, const float* __restrict__ gb2,
    const float* __restrict__ pmind, const float* __restrict__ pmaxd,
    float* __restrict__ out, u16* __restrict__ outB) {
  const int b = blockIdx.x, t = threadIdx.x;
  const int w = t >> 6, lane = t & 63;
  const int drift = (w < 4) ? 1 : 0;
  const int wseg = w & 3;                 // K-segment index 0..3

  __shared__ float y_s[8][64];            // per-wave private y copy
  __shared__ float h1seg[8][32];          // per-wave A output segment
  __shared__ float h2c[8][64];            // per-wave private h2 copy
  __shared__ float pd[2][4][64];          // drift B partials (parity dbuf)
  __shared__ float pg[2][4][64];          // diffusion B partials
  __shared__ float tl_s[512], hs_s[512], sq_s[512];

  const float mind = fabsf(pmind[0]);
  const float maxd = fabsf(pmaxd[0]);

  // ---- stage A weights: out col = wseg*32 + (lane>>1), hA = K-half ----
  const int colA = wseg * 32 + (lane >> 1);
  const int hA = lane & 1;
  const float* W1 = drift ? dW1 : gW1;
  float wA[32];
#pragma unroll
  for (int k = 0; k < 32; k++) wA[k] = W1[(hA * 32 + k) * 128 + colA];
  const float wAt = W1[64 * 128 + colA];
  const float bA = (drift ? db1 : gb1)[colA];

  // ---- stage B partial weights: out col = lane, K rows wseg*32.. ----
  const float* W2 = drift ? dW2 : gW2;
  float wB[32];
#pragma unroll
  for (int k = 0; k < 32; k++) wB[k] = W2[(wseg * 32 + k) * 64 + lane];
  const float bBd = db2[lane], bBg = gb2[lane];

  // ---- stage C weights (every wave, redundant): out col = lane ----
  float wC[64];
#pragma unroll
  for (int k = 0; k < 64; k++) wC[k] = dW3[k * 64 + lane];
  const float bC = db3[lane];

  // ---- prologue ----
  tl_s[t & 511] = ts[(t & 511) * 3];
  __syncthreads();
  if (t < 511) {
    float hh = tl_s[t + 1] - tl_s[t];
    hs_s[t] = hh;
    sq_s[t] = sqrtf(hh);
  }

  float ymine = 0.1f;
  if (lane < 3) ymine = fminf(fmaxf(ts[b * 1536 + lane], 0.01f), 10.f);
  y_s[w][lane] = ymine;
  if (w == 0) out[(long)b * 32768 + lane] = ymine;
  if (w == 1) outB[((long)b * 512) * 64 + lane] = f2b(ymine);

  const long nofs = (long)b * 64 + lane;
  float nz0 = noise[nofs];
  float nz1 = noise[4096 + nofs];
  float nz2 = noise[2 * 4096 + nofs];
  float nz3 = noise[3 * 4096 + nofs];
  __syncthreads();

  for (int i = 0; i < 511; i++) {
    const int buf = i & 1;
    const float tl = tl_s[i];
    const float hh = hs_s[i];
    const float sq = sq_s[i];

    // noise shift-register (compile-time slots)
    const float nz = nz0;
    nz0 = nz1; nz1 = nz2; nz2 = nz3;
    if (i + 4 < 511) nz3 = noise[(long)(i + 4) * 4096 + nofs];

    // ---- stage A: 2 lanes/out, 32 MACs, own y copy (broadcast reads) ----
    float a0 = 0.f, a1 = 0.f, a2 = 0.f, a3 = 0.f;
#pragma unroll
    for (int g = 0; g < 8; g++) {
      float4 yv = *(const float4*)&y_s[w][hA * 32 + g * 4];
      a0 += yv.x * wA[g * 4 + 0];
      a1 += yv.y * wA[g * 4 + 1];
      a2 += yv.z * wA[g * 4 + 2];
      a3 += yv.w * wA[g * 4 + 3];
    }
    float p1 = (a0 + a1) + (a2 + a3);
    p1 += hA ? (tl * wAt) : bA;
    p1 = dpp_xor1_add(p1);                // VALU pair-combine (no LDS pipe)
    float h1v = fast_tanh(p1);
    if (hA == 0) h1seg[w][lane >> 1] = h1v;
    // intra-wave handoff: no barrier

    // ---- stage B partial: 32 MACs over own segment (broadcast reads) ----
    float c0 = 0.f, c1 = 0.f, c2 = 0.f, c3 = 0.f;
#pragma unroll
    for (int g = 0; g < 8; g++) {
      float4 hv = *(const float4*)&h1seg[w][g * 4];
      c0 += hv.x * wB[g * 4 + 0];
      c1 += hv.y * wB[g * 4 + 1];
      c2 += hv.z * wB[g * 4 + 2];
      c3 += hv.w * wB[g * 4 + 3];
    }
    float psum = (c0 + c1) + (c2 + c3);
    if (drift) pd[buf][wseg][lane] = psum;
    else       pg[buf][wseg][lane] = psum;

    barrier_lds();                        // the ONE barrier per step

    // ---- reduce (redundant per wave): h2[lane], gc[lane] ----
    float sd = ((pd[buf][0][lane] + pd[buf][1][lane]) +
                (pd[buf][2][lane] + pd[buf][3][lane])) + bBd;
    float h2v = fast_tanh(sd);
    float sg = ((pg[buf][0][lane] + pg[buf][1][lane]) +
                (pg[buf][2][lane] + pg[buf][3][lane])) + bBg;
    float gc = fmaxf(sg, 0.f) + __logf(1.f + __expf(-fabsf(sg))) + mind;
    h2c[w][lane] = h2v;
    // intra-wave handoff: no barrier

    // ---- stage C (redundant per wave): 64 MACs, broadcast reads ----
    float d0 = 0.f, d1 = 0.f, d2 = 0.f, d3 = 0.f;
#pragma unroll
    for (int g = 0; g < 16; g++) {
      float4 hv = *(const float4*)&h2c[w][g * 4];
      d0 += hv.x * wC[g * 4 + 0];
      d1 += hv.y * wC[g * 4 + 1];
      d2 += hv.z * wC[g * 4 + 2];
      d3 += hv.w * wC[g * 4 + 3];
    }
    float dc = fminf(fmaxf((d0 + d1) + (d2 + d3) + bC, -maxd), maxd);

    // ---- y update (redundant per wave, own copy) ----
    float yo = ymine;
    float yn = yo + dc * yo * hh + gc * fminf(fmaxf(yo, -10.f), 10.f) * nz * sq;
    yn = fminf(fmaxf(yn, 0.01f), 10.f);
    y_s[w][lane] = yn;
    ymine = yn;
    if (w == 0) out[(long)b * 32768 + (i + 1) * 64 + lane] = yn;
    if (w == 1) outB[((long)b * 512 + i + 1) * 64 + lane] = f2b(yn);
  }
}

// ---------------------------------------------------------------------------
__global__ __launch_bounds__(256) void prep_weights(
    const float* __restrict__ in_W, const float* __restrict__ Wq,
    const float* __restrict__ Wk, const float* __restrict__ Wv,
    const float* __restrict__ Wo, const float* __restrict__ fW1,
    const float* __restrict__ fW2,
    u16* __restrict__ inWt, u16* __restrict__ qkvWt, u16* __restrict__ Wot,
    u16* __restrict__ fW1t, u16* __restrict__ fW2t) {
  const int z = blockIdx.z, layer = blockIdx.y, tile = blockIdx.x;
  const float* src; u16* dst; int R, C, nl;
  switch (z) {
    case 0: src = in_W; dst = inWt; R = 64; C = 128; nl = 1; break;
    case 1: src = Wq + layer * 16384; dst = qkvWt + layer * 49152; R = 128; C = 128; nl = 4; break;
    case 2: src = Wk + layer * 16384; dst = qkvWt + layer * 49152 + 16384; R = 128; C = 128; nl = 4; break;
    case 3: src = Wv + layer * 16384; dst = qkvWt + layer * 49152 + 32768; R = 128; C = 128; nl = 4; break;
    case 4: src = Wo + layer * 16384; dst = Wot + layer * 16384; R = 128; C = 128; nl = 4; break;
    case 5: src = fW1 + layer * 65536; dst = fW1t + layer * 65536; R = 128; C = 512; nl = 4; break;
    default: src = fW2 + layer * 65536; dst = fW2t + layer * 65536; R = 512; C = 128; nl = 4; break;
  }
  const int nt = (R / 32) * (C / 32);
  if (layer >= nl || tile >= nt) return;
  const int tpr = C / 32;
  const int r0 = (tile / tpr) * 32, c0 = (tile % tpr) * 32;
  __shared__ float tl[32][33];
  const int tx = threadIdx.x & 31, ty = threadIdx.x >> 5;
#pragma unroll
  for (int p = 0; p < 4; p++)
    tl[ty + 8 * p][tx] = src[(long)(r0 + ty + 8 * p) * C + c0 + tx];
  __syncthreads();
#pragma unroll
  for (int p = 0; p < 4; p++)
    dst[(long)(c0 + ty + 8 * p) * R + r0 + tx] = f2b(tl[tx][ty + 8 * p]);
}

// ---------------------------------------------------------------------------
// bf16 MFMA GEMM (bf16 out). Used once for x = sde @ in_W.
// ---------------------------------------------------------------------------
__global__ __launch_bounds__(256) void mfma_gemm(
    const u16* __restrict__ A, const u16* __restrict__ Bt,
    const float* __restrict__ bias, u16* __restrict__ outB, int K, int N) {
  __shared__ u16 As[128 * 40];
  __shared__ u16 Bs[64 * 40];
  const int t = threadIdx.x;
  const int nb = blockIdx.x * 64;
  const long mb = (long)blockIdx.y * 128;
  const int lane = t & 63, wave = t >> 6;
  const int wm = (wave >> 1) * 64, wn = (wave & 1) * 32;
  const int fr = lane & 15, quad = lane >> 4;

  f32x4 zero = {0.f, 0.f, 0.f, 0.f};
  f32x4 acc[4][2];
#pragma unroll
  for (int mi = 0; mi < 4; mi++)
#pragma unroll
    for (int ni = 0; ni < 2; ni++) acc[mi][ni] = zero;

  for (int k0 = 0; k0 < K; k0 += 32) {
#pragma unroll
    for (int p = 0; p < 2; p++) {
      int idx = t + p * 256, row = idx >> 2, seg = idx & 3;
      int4 v = *(const int4*)&A[(mb + row) * K + k0 + seg * 8];
      *(int4*)&As[row * 40 + seg * 8] = v;
    }
    {
      int row = t >> 2, seg = t & 3;
      int4 v = *(const int4*)&Bt[(long)(nb + row) * K + k0 + seg * 8];
      *(int4*)&Bs[row * 40 + seg * 8] = v;
    }
    __syncthreads();
    bf16x8 af[4], bfr[2];
#pragma unroll
    for (int mi = 0; mi < 4; mi++)
      af[mi] = *(const bf16x8*)&As[(wm + mi * 16 + fr) * 40 + quad * 8];
#pragma unroll
    for (int ni = 0; ni < 2; ni++)
      bfr[ni] = *(const bf16x8*)&Bs[(wn + ni * 16 + fr) * 40 + quad * 8];
#pragma unroll
    for (int mi = 0; mi < 4; mi++)
#pragma unroll
      for (int ni = 0; ni < 2; ni++)
        acc[mi][ni] = __builtin_amdgcn_mfma_f32_16x16x32_bf16(
            af[mi], bfr[ni], acc[mi][ni], 0, 0, 0);
    __syncthreads();
  }

#pragma unroll
  for (int mi = 0; mi < 4; mi++)
#pragma unroll
    for (int ni = 0; ni < 2; ni++) {
      int col = nb + wn + ni * 16 + fr;
      float bv = bias[col];
#pragma unroll
      for (int r = 0; r < 4; r++) {
        long row = mb + wm + mi * 16 + quad * 4 + r;
        outB[row * N + col] = f2b(acc[mi][ni][r] + bv);
      }
    }
}

// ---------------------------------------------------------------------------
// layer_tail (round-9 v1, verified): x <- LN2( x' + relu(x'@W1+b1)@W2+b2 ),
// x' = LN1(x + o@Wo+bo). 512 blocks x 512 thr, 1 block/CU (~89 KB LDS).
// All B-operands streamed from L2. x' kept in registers for the FFN2
// residual; staged once in LDS for the FFN1 A-fragments. LN stats via DPP
// red16 + owner-lane pass. (v2's 2-chunk + VGPR-128 cap regressed ~+100us —
// spills; reverted.)
// ---------------------------------------------------------------------------
__global__ __launch_bounds__(512, 1) void layer_tail(
    const u16* __restrict__ ob, const u16* __restrict__ Wot,
    const float* __restrict__ bo, const float* __restrict__ ln1s,
    const float* __restrict__ ln1b, const u16* __restrict__ W1t,
    const float* __restrict__ fb1, const u16* __restrict__ W2t,
    const float* __restrict__ fb2, const float* __restrict__ ln2s,
    const float* __restrict__ ln2b, u16* __restrict__ xb) {
  __shared__ u16 As[64 * 136];        // attn-out tile, then x' tile
  __shared__ u16 Hs[64 * 520];        // hidden tile
  __shared__ float s1[64][8], s2[64][8];
  __shared__ float mst[64][2];
  const int t = threadIdx.x;
  const long mb = (long)blockIdx.x * 64;
  const int w = t >> 6, lane = t & 63;
  const int fr = lane & 15, quad = lane >> 4;
  const int col = w * 16 + fr;        // this thread's output column
  const f32x4 z4 = {0.f, 0.f, 0.f, 0.f};

  // ---- stage attn-out tile 64x128 ----
#pragma unroll
  for (int p = 0; p < 2; p++) {
    int c = t + p * 512;
    int row = c >> 4, sub = c & 15;
    *(int4*)&As[row * 136 + sub * 8] =
        *(const int4*)&ob[(mb + row) * DD + sub * 8];
  }
  __syncthreads();

  // ---- attn-out projection: o @ Wo (K=128), B streamed from L2 ----
  bf16x8 af[4][4];
#pragma unroll
  for (int m = 0; m < 4; m++)
#pragma unroll
    for (int c = 0; c < 4; c++)
      af[m][c] = *(const bf16x8*)&As[(m * 16 + fr) * 136 + c * 32 + quad * 8];

  f32x4 acc[4] = {z4, z4, z4, z4};
#pragma unroll
  for (int kc = 0; kc < 4; kc++) {
    bf16x8 bfr = *(const bf16x8*)&Wot[col * 128 + kc * 32 + quad * 8];
#pragma unroll
    for (int m = 0; m < 4; m++)
      acc[m] = __builtin_amdgcn_mfma_f32_16x16x32_bf16(af[m][kc], bfr,
                                                       acc[m], 0, 0, 0);
  }

  // ---- residual + LN1 partials ----
  const float bov = bo[col], g1 = ln1s[col], be1 = ln1b[col];
  float vv[4][4];
#pragma unroll
  for (int m = 0; m < 4; m++)
#pragma unroll
    for (int r = 0; r < 4; r++) {
      int row = m * 16 + quad * 4 + r;
      float v = acc[m][r] + bov + b2f(xb[(mb + row) * DD + col]);
      vv[m][r] = v;
      float s = red16(v);
      float ss = red16(v * v);
      if (fr == 0) { s1[row][w] = s; s2[row][w] = ss; }
    }
  __syncthreads();
  {
    int row = lane;
    float4 a = *(const float4*)&s1[row][0];
    float4 bq4 = *(const float4*)&s1[row][4];
    float sumv = ((a.x + a.y) + (a.z + a.w)) +
                 ((bq4.x + bq4.y) + (bq4.z + bq4.w));
    float4 cq = *(const float4*)&s2[row][0];
    float4 dq = *(const float4*)&s2[row][4];
    float sumsq = ((cq.x + cq.y) + (cq.z + cq.w)) +
                  ((dq.x + dq.y) + (dq.z + dq.w));
    float mean = sumv * (1.f / 128.f);
    float var = sumsq * (1.f / 128.f) - mean * mean;
    mst[row][0] = mean;
    mst[row][1] = rsqrtf(var + 1e-5f);
  }
  __syncthreads();

  // ---- x' = LN1(...): keep in regs (FFN2 residual) + stage in LDS ----
  float xr[4][4];
#pragma unroll
  for (int m = 0; m < 4; m++)
#pragma unroll
    for (int r = 0; r < 4; r++) {
      int row = m * 16 + quad * 4 + r;
      float xv = (vv[m][r] - mst[row][0]) * mst[row][1] * g1 + be1;
      xr[m][r] = xv;
      As[row * 136 + col] = f2b(xv);
    }
  __syncthreads();

  // ---- FFN1: A-frags from x', W1 streamed; wave covers 4 col-tiles ----
  bf16x8 af2[4][4];
#pragma unroll
  for (int m = 0; m < 4; m++)
#pragma unroll
    for (int c = 0; c < 4; c++)
      af2[m][c] = *(const bf16x8*)&As[(m * 16 + fr) * 136 + c * 32 + quad * 8];

#pragma unroll
  for (int nn = 0; nn < 4; nn++) {
    const int nt = w * 4 + nn;
    bf16x8 bfr[4];
#pragma unroll
    for (int c = 0; c < 4; c++)
      bfr[c] = *(const bf16x8*)&W1t[(nt * 16 + fr) * 128 + c * 32 + quad * 8];
    f32x4 a1[4] = {z4, z4, z4, z4};
#pragma unroll
    for (int c = 0; c < 4; c++)
#pragma unroll
      for (int m = 0; m < 4; m++)
        a1[m] = __builtin_amdgcn_mfma_f32_16x16x32_bf16(af2[m][c], bfr[c],
                                                        a1[m], 0, 0, 0);
    const float bv = fb1[nt * 16 + fr];
#pragma unroll
    for (int m = 0; m < 4; m++)
#pragma unroll
      for (int r = 0; r < 4; r++)
        Hs[(m * 16 + quad * 4 + r) * 520 + nt * 16 + fr] =
            f2b(fmaxf(a1[m][r] + bv, 0.f));
  }
  __syncthreads();

  // ---- FFN2: K=512, W2 streamed; wave covers out cols w*16.. ----
  f32x4 acc2[4] = {z4, z4, z4, z4};
#pragma unroll
  for (int kc = 0; kc < 16; kc++) {
    bf16x8 bfr2 = *(const bf16x8*)&W2t[col * 512 + kc * 32 + quad * 8];
    bf16x8 a2[4];
#pragma unroll
    for (int m = 0; m < 4; m++)
      a2[m] = *(const bf16x8*)&Hs[(m * 16 + fr) * 520 + kc * 32 + quad * 8];
#pragma unroll
    for (int m = 0; m < 4; m++)
      acc2[m] = __builtin_amdgcn_mfma_f32_16x16x32_bf16(a2[m], bfr2,
                                                        acc2[m], 0, 0, 0);
  }

  // ---- residual (from regs!) + LN2 ----
  const float bv2 = fb2[col], g2 = ln2s[col], be2 = ln2b[col];
#pragma unroll
  for (int m = 0; m < 4; m++)
#pragma unroll
    for (int r = 0; r < 4; r++) {
      int row = m * 16 + quad * 4 + r;
      float v = acc2[m][r] + bv2 + xr[m][r];
      vv[m][r] = v;
      float s = red16(v);
      float ss = red16(v * v);
      if (fr == 0) { s1[row][w] = s; s2[row][w] = ss; }
    }
  __syncthreads();
  {
    int row = lane;
    float4 a = *(const float4*)&s1[row][0];
    float4 bq4 = *(const float4*)&s1[row][4];
    float sumv = ((a.x + a.y) + (a.z + a.w)) +
                 ((bq4.x + bq4.y) + (bq4.z + bq4.w));
    float4 cq = *(const float4*)&s2[row][0];
    float4 dq = *(const float4*)&s2[row][4];
    float sumsq = ((cq.x + cq.y) + (cq.z + cq.w)) +
                  ((dq.x + dq.y) + (dq.z + dq.w));
    float mean = sumv * (1.f / 128.f);
    float var = sumsq * (1.f / 128.f) - mean * mean;
    mst[row][0] = mean;
    mst[row][1] = rsqrtf(var + 1e-5f);
  }
  __syncthreads();

#pragma unroll
  for (int m = 0; m < 4; m++)
#pragma unroll
    for (int r = 0; r < 4; r++) {
      int row = m * 16 + quad * 4 + r;
      xb[(mb + row) * DD + col] =
          f2b((vv[m][r] - mst[row][0]) * mst[row][1] * g2 + be2);
    }
}

// ---------------------------------------------------------------------------
// Fused QKV-projection + flash attention. One block per (b,h), 512 blocks.
// v5 (kept from r10 for clean A/B): Qs array (24 KB) deleted — each wave
// produces and consumes ITS OWN q-tiles (tile = qt = w+4k), so Q goes
// through a 768 B per-wave LDS scratch round-trip (write -> lgkmcnt ->
// read, no barrier) into 8 register fragments. LDS 64.3 -> 43.3 KB =>
// 3 blocks/CU (__launch_bounds__(256,3), VGPR cap 168 — comfortable).
// V at permuted slots tau (no ds_bpermute); no-max exp2 softmax with
// cvt_pk packing (verified r9).
// ---------------------------------------------------------------------------
__global__ __launch_bounds__(256, 3) void qkv_attn(
    const u16* __restrict__ xb, const u16* __restrict__ qkvW,
    const float* __restrict__ bq, const float* __restrict__ bk,
    const float* __restrict__ bv, u16* __restrict__ Og) {
  const int bh = blockIdx.x;
  const int b = bh >> 3, h = bh & 7;
  __shared__ u16 Ks[512 * 24];     // [key][d]  (24 KB)
  __shared__ u16 Vt[16 * 520];     // [d][key-slot]  (16.3 KB)
  __shared__ u16 Qsc[4][16 * 24];  // per-wave Q transpose scratch (3 KB)
  const int t = threadIdx.x;
  const int w = t >> 6, lane = t & 63;
  const int fr = lane & 15, quad = lane >> 4;
  const long obase = ((long)b * SS) * DD + h * 16;
  const u16* xrow = xb + (long)b * SS * DD;

  // ---- head weight B-frags (register-resident) ----
  const u16* Wq_h = qkvW + (h * 16) * 128;
  const u16* Wk_h = qkvW + 16384 + (h * 16) * 128;
  const u16* Wv_h = qkvW + 32768 + (h * 16) * 128;
  bf16x8 wqf[4], wkf[4], wvf[4];
#pragma unroll
  for (int c = 0; c < 4; c++) {
    wqf[c] = *(const bf16x8*)&Wq_h[fr * 128 + c * 32 + quad * 8];
    wkf[c] = *(const bf16x8*)&Wk_h[fr * 128 + c * 32 + quad * 8];
    wvf[c] = *(const bf16x8*)&Wv_h[fr * 128 + c * 32 + quad * 8];
  }
  const float bqv = bq[h * 16 + fr];
  const float bkv = bk[h * 16 + fr];
  const float bvv = bv[h * 16 + fr];
  const f32x4 z4 = {0.f, 0.f, 0.f, 0.f};
  const float qscale = 0.25f * 1.4426950408889634f;  // 1/sqrt(16) * log2(e)

  // ---- project Q/K/V; Q kept in per-wave register frags ----
  bf16x8 qreg[8];
#pragma unroll
  for (int ti = 0; ti < 8; ti++) {
    const int t0 = (w + ti * 4) * 16;
    bf16x8 af[4];
#pragma unroll
    for (int c = 0; c < 4; c++)
      af[c] = *(const bf16x8*)&xrow[(t0 + fr) * 128 + c * 32 + quad * 8];
    f32x4 qa = z4, ka = z4, va = z4;
#pragma unroll
    for (int c = 0; c < 4; c++) {
      qa = __builtin_amdgcn_mfma_f32_16x16x32_bf16(af[c], wqf[c], qa, 0, 0, 0);
      ka = __builtin_amdgcn_mfma_f32_16x16x32_bf16(af[c], wkf[c], ka, 0, 0, 0);
      va = __builtin_amdgcn_mfma_f32_16x16x32_bf16(af[c], wvf[c], va, 0, 0, 0);
    }
    // C-layout: lane holds (d = fr, row = t0 + quad*4 + r)
#pragma unroll
    for (int r = 0; r < 4; r++) {
      int row = t0 + quad * 4 + r;
      Ks[row * 24 + fr] = f2b(ka[r] + bkv);
      Qsc[w][(quad * 4 + r) * 24 + fr] = f2b((qa[r] + bqv) * qscale);
    }
    // V: permuted slots (tau), 4 consecutive rows -> one b64 write.
    {
      const int t0q = t0 + quad * 4;
      const int r40 = t0q & 31;
      const int vbase = (t0q & ~31) + ((r40 & 12) << 1) + ((r40 & 16) >> 2);
      uint2 vvv;
      vvv.x = cvt_pk_bf16(va[0] + bvv, va[1] + bvv);
      vvv.y = cvt_pk_bf16(va[2] + bvv, va[3] + bvv);
      *(uint2*)&Vt[fr * 520 + vbase] = vvv;
    }
    // wave-local Q transpose round-trip (no barrier)
    wait_lds();
    bf16x8 qf = {0, 0, 0, 0, 0, 0, 0, 0};
    if (quad < 2)
      qf = *(const bf16x8*)&Qsc[w][fr * 24 + quad * 8];
    qreg[ti] = qf;
  }
  __syncthreads();

  // ---- flash attention (S^T orientation, no-max exp2 softmax) ----
#pragma unroll
  for (int ti = 0; ti < 8; ti++) {
    const int q0 = (w + ti * 4) * 16;
    const bf16x8 qf = qreg[ti];
    f32x4 oacc = {0.f, 0.f, 0.f, 0.f};
    float rsacc = 0.f;                 // per-lane partial l (reduced once)

    for (int kt = 0; kt < 16; kt++) {
      const int k0 = kt * 32;
      bf16x8 kf0 = {0, 0, 0, 0, 0, 0, 0, 0};
      bf16x8 kf1 = {0, 0, 0, 0, 0, 0, 0, 0};
      if (quad < 2) {
        kf0 = *(const bf16x8*)&Ks[(k0 + fr) * 24 + quad * 8];
        kf1 = *(const bf16x8*)&Ks[(k0 + 16 + fr) * 24 + quad * 8];
      }
      f32x4 slo = __builtin_amdgcn_mfma_f32_16x16x32_bf16(kf0, qf, z4, 0, 0, 0);
      f32x4 shi = __builtin_amdgcn_mfma_f32_16x16x32_bf16(kf1, qf, z4, 0, 0, 0);
      float p[8];
#pragma unroll
      for (int r = 0; r < 4; r++) {
        p[r] = __builtin_amdgcn_exp2f(slo[r]);
        p[4 + r] = __builtin_amdgcn_exp2f(shi[r]);
      }
      rsacc += ((p[0] + p[1]) + (p[2] + p[3])) +
               ((p[4] + p[5]) + (p[6] + p[7]));

      // native packed P words ARE the B-frag (V slots pre-permuted)
      union { unsigned i[4]; bf16x8 v; } pu;
      pu.i[0] = cvt_pk_bf16(p[0], p[1]);
      pu.i[1] = cvt_pk_bf16(p[2], p[3]);
      pu.i[2] = cvt_pk_bf16(p[4], p[5]);
      pu.i[3] = cvt_pk_bf16(p[6], p[7]);
      bf16x8 vf = *(const bf16x8*)&Vt[fr * 520 + k0 + quad * 8];
      oacc = __builtin_amdgcn_mfma_f32_16x16x32_bf16(vf, pu.v, oacc, 0, 0, 0);
    }

    float lrun = rsacc;
    lrun += __shfl_xor(lrun, 16);
    lrun += __shfl_xor(lrun, 32);
    float inv = __fdividef(1.f, lrun);
    uint2 o;
    o.x = cvt_pk_bf16(oacc[0] * inv, oacc[1] * inv);
    o.y = cvt_pk_bf16(oacc[2] * inv, oacc[3] * inv);
    *(uint2*)&Og[obase + (long)(q0 + fr) * DD + quad * 4] = o;
  }
}

// ---------------------------------------------------------------------------
__global__ __launch_bounds__(512) void pool_kernel(const u16* __restrict__ X,
                                                   float* __restrict__ P) {
  const int b = blockIdx.x, t = threadIdx.x;
  const int c = t & 127, sg = t >> 7;       // 4 s-groups
  __shared__ float red[4][128];
  float acc = 0.f;
  for (int s = sg; s < SS; s += 4)
    acc += b2f(X[((long)b * SS + s) * DD + c]);
  red[sg][c] = acc;
  __syncthreads();
  if (t < 128)
    P[b * DD + t] =
        (red[0][t] + red[1][t] + red[2][t] + red[3][t]) * (1.f / 512.f);
}

__global__ __launch_bounds__(64) void cls_kernel(
    const float* __restrict__ P, const float* __restrict__ W1,
    const float* __restrict__ b1, const float* __restrict__ W2,
    const float* __restrict__ b2, float* __restrict__ L) {
  const int b = blockIdx.x, t = threadIdx.x;
  __shared__ float sp[128];
  __shared__ float sh[64];
  sp[t] = P[b * DD + t];
  sp[t + 64] = P[b * DD + 64 + t];
  __syncthreads();
  float acc = b1[t];
  for (int k = 0; k < 128; k++) acc += sp[k] * W1[k * 64 + t];
  sh[t] = fmaxf(acc, 0.f);
  __syncthreads();
  if (t < 5) {
    float acc2 = b2[t];
    for (int k = 0; k < 64; k++) acc2 += sh[k] * W2[k * 5 + t];
    L[b * 5 + t] = acc2;
  }
}

// ---------------------------------------------------------------------------
extern "C" void kernel_launch(void* const* d_in, const int* in_sizes, int n_in,
                              void* d_out, int out_size, void* d_ws, size_t ws_size,
                              hipStream_t stream) {
  const float* ts    = (const float*)d_in[0];
  const float* noise = (const float*)d_in[2];
  const float* dW1   = (const float*)d_in[3];
  const float* db1   = (const float*)d_in[4];
  const float* dW2   = (const float*)d_in[5];
  const float* db2   = (const float*)d_in[6];
  const float* dW3   = (const float*)d_in[7];
  const float* db3   = (const float*)d_in[8];
  const float* gW1   = (const float*)d_in[9];
  const float* gb1   = (const float*)d_in[10];
  const float* gW2   = (const float*)d_in[11];
  const float* gb2   = (const float*)d_in[12];
  const float* mind  = (const float*)d_in[13];
  const float* maxd  = (const float*)d_in[14];
  const float* in_W  = (const float*)d_in[15];
  const float* in_b  = (const float*)d_in[16];
  const float* Wq    = (const float*)d_in[17];
  const float* bq    = (const float*)d_in[18];
  const float* Wk    = (const float*)d_in[19];
  const float* bk    = (const float*)d_in[20];
  const float* Wv    = (const float*)d_in[21];
  const float* bv    = (const float*)d_in[22];
  const float* Wo    = (const float*)d_in[23];
  const float* bo    = (const float*)d_in[24];
  const float* ln1s  = (const float*)d_in[25];
  const float* ln1b  = (const float*)d_in[26];
  const float* fW1   = (const float*)d_in[27];
  const float* fb1   = (const float*)d_in[28];
  const float* fW2   = (const float*)d_in[29];
  const float* fb2   = (const float*)d_in[30];
  const float* ln2s  = (const float*)d_in[31];
  const float* ln2b  = (const float*)d_in[32];
  const float* cW1   = (const float*)d_in[33];
  const float* cb1   = (const float*)d_in[34];
  const float* cW2   = (const float*)d_in[35];
  const float* cb2   = (const float*)d_in[36];

  float* logits = (float*)d_out;
  float* sde    = logits + BB * 5;

  // Workspace (all-bf16 residual stream):
  char* W = (char*)d_ws;
  u16*  bxb    = (u16*)(W);                   //  8 MB bf16 x
  u16*  bob    = (u16*)(W + (40u << 20));     //  8 MB bf16 attn out
  u16*  bsb    = (u16*)(W + (48u << 20));     //  4 MB bf16 sde feats
  u16*  wts    = (u16*)(W + (52u << 20));     // ~1.5 MB bf16 weights
  float* bp    = (float*)(W + (54u << 20));   // pooled 64x128

  u16* inWt  = wts;                 // [128][64]
  u16* qkvWt = inWt + 8192;         // [4][3][128][128]
  u16* Wot   = qkvWt + 196608;      // [4][128][128]
  u16* fW1t  = Wot + 65536;         // [4][512][128]
  u16* fW2t  = fW1t + 262144;       // [4][128][512]

  prep_weights<<<dim3(64, 4, 7), 256, 0, stream>>>(in_W, Wq, Wk, Wv, Wo, fW1, fW2,
                                                   inWt, qkvWt, Wot, fW1t, fW2t);

  sde_kernel<<<64, 512, 0, stream>>>(ts, noise, dW1, db1, dW2, db2, dW3, db3,
                                     gW1, gb1, gW2, gb2, mind, maxd, sde, bsb);

  // x = sde @ in_W + in_b  (bf16)
  mfma_gemm<<<dim3(2, 256), 256, 0, stream>>>(bsb, inWt, in_b, bxb, 64, 128);

  for (int l = 0; l < 4; l++) {
    qkv_attn<<<BB * NHD, 256, 0, stream>>>(bxb, qkvWt + l * 49152,
                                           bq + l * DD, bk + l * DD, bv + l * DD,
                                           bob);
    layer_tail<<<512, 512, 0, stream>>>(bob, Wot + l * 16384, bo + l * DD,
                                        ln1s + l * DD, ln1b + l * DD,
                                        fW1t + l * 65536, fb1 + l * 512,
                                        fW2t + l * 65536, fb2 + l * DD,
                                        ln2s + l * DD, ln2b + l * DD, bxb);
  }

  pool_kernel<<<BB, 512, 0, stream>>>(bxb, bp);
  cls_kernel<<<BB, 64, 0, stream>>>(bp, cW1, cb1, cW2, cb2, logits);
}

// Round 12
// 1044.354 us; speedup vs baseline: 1.1256x; 1.1256x over previous
//
#include <hip/hip_runtime.h>
#include <hip/hip_bf16.h>
#include <math.h>

#define BB 64
#define SS 512
#define HH 64
#define DD 128
#define NHD 8
#define ROWS (BB*SS)   // 32768

typedef unsigned short u16;
typedef __attribute__((ext_vector_type(8))) short bf16x8;
typedef __attribute__((ext_vector_type(4))) float f32x4;

__device__ __forceinline__ u16 f2b(float f) {
  union { float f; unsigned u; } x; x.f = f;
  unsigned r = x.u + 0x7fffu + ((x.u >> 16) & 1u);
  return (u16)(r >> 16);
}

__device__ __forceinline__ float b2f(u16 u) {
  return __uint_as_float(((unsigned)u) << 16);
}

// packed bf16 convert (RNE), 1 instruction for 2 values.
__device__ __forceinline__ unsigned cvt_pk_bf16(float lo, float hi) {
  unsigned r;
  asm("v_cvt_pk_bf16_f32 %0, %1, %2" : "=v"(r) : "v"(lo), "v"(hi));
  return r;
}

__device__ __forceinline__ float fast_tanh(float x) {
  float ax = fminf(fabsf(x), 15.f);
  float e = __expf(2.f * ax);
  float r = 1.f - __fdividef(2.f, e + 1.f);
  return copysignf(r, x);
}

__device__ __forceinline__ void barrier_lds() {
  __builtin_amdgcn_s_waitcnt(0xC07F);   // lgkmcnt(0) only
  __builtin_amdgcn_s_barrier();
}

// pair-combine via DPP (VALU, not LDS pipe): add value of lane^1
__device__ __forceinline__ float dpp_xor1_add(float x) {
  int pi = __float_as_int(x);
  int po = __builtin_amdgcn_update_dpp(0, pi, 0xB1 /*quad_perm [1,0,3,2]*/,
                                       0xF, 0xF, true);
  return x + __int_as_float(po);
}

template <int CTRL>
__device__ __forceinline__ float dpp_add(float x) {
  int po = __builtin_amdgcn_update_dpp(0, __float_as_int(x), CTRL, 0xF, 0xF, true);
  return x + __int_as_float(po);
}
// sum across each 16-lane group, all on the VALU pipe
__device__ __forceinline__ float red16(float x) {
  x = dpp_add<0xB1>(x);    // quad_perm xor1
  x = dpp_add<0x4E>(x);    // quad_perm xor2
  x = dpp_add<0x141>(x);   // row_half_mirror (combines 4-groups)
  x = dpp_add<0x140>(x);   // row_mirror (combines 8-halves)
  return x;
}

// ---------------------------------------------------------------------------
// SDE scan v10 (verified 577 us): 8 waves (0-3 drift, 4-7 diffusion), ONE
// barrier per step, K-segmented stage B, redundant reduce + LDS-staged
// stage C per wave, per-wave private y. Stable local optimum — frozen.
// ---------------------------------------------------------------------------
__global__ __attribute__((amdgpu_flat_work_group_size(512, 512)))
__attribute__((amdgpu_waves_per_eu(2, 2))) void sde_kernel(
    const float* __restrict__ ts, const float* __restrict__ noise,
    const float* __restrict__ dW1, const float* __restrict__ db1,
    const float* __restrict__ dW2, const float* __restrict__ db2,
    const float* __restrict__ dW3, const float* __restrict__ db3,
    const float* __restrict__ gW1, const float* __restrict__ gb1,
    const float* __restrict__ gW2, const float* __restrict__ gb2,
    const float* __restrict__ pmind, const float* __restrict__ pmaxd,
    float* __restrict__ out, u16* __restrict__ outB) {
  const int b = blockIdx.x, t = threadIdx.x;
  const int w = t >> 6, lane = t & 63;
  const int drift = (w < 4) ? 1 : 0;
  const int wseg = w & 3;                 // K-segment index 0..3

  __shared__ float y_s[8][64];            // per-wave private y copy
  __shared__ float h1seg[8][32];          // per-wave A output segment
  __shared__ float h2c[8][64];            // per-wave private h2 copy
  __shared__ float pd[2][4][64];          // drift B partials (parity dbuf)
  __shared__ float pg[2][4][64];          // diffusion B partials
  __shared__ float tl_s[512], hs_s[512], sq_s[512];

  const float mind = fabsf(pmind[0]);
  const float maxd = fabsf(pmaxd[0]);

  // ---- stage A weights: out col = wseg*32 + (lane>>1), hA = K-half ----
  const int colA = wseg * 32 + (lane >> 1);
  const int hA = lane & 1;
  const float* W1 = drift ? dW1 : gW1;
  float wA[32];
#pragma unroll
  for (int k = 0; k < 32; k++) wA[k] = W1[(hA * 32 + k) * 128 + colA];
  const float wAt = W1[64 * 128 + colA];
  const float bA = (drift ? db1 : gb1)[colA];

  // ---- stage B partial weights: out col = lane, K rows wseg*32.. ----
  const float* W2 = drift ? dW2 : gW2;
  float wB[32];
#pragma unroll
  for (int k = 0; k < 32; k++) wB[k] = W2[(wseg * 32 + k) * 64 + lane];
  const float bBd = db2[lane], bBg = gb2[lane];

  // ---- stage C weights (every wave, redundant): out col = lane ----
  float wC[64];
#pragma unroll
  for (int k = 0; k < 64; k++) wC[k] = dW3[k * 64 + lane];
  const float bC = db3[lane];

  // ---- prologue ----
  tl_s[t & 511] = ts[(t & 511) * 3];
  __syncthreads();
  if (t < 511) {
    float hh = tl_s[t + 1] - tl_s[t];
    hs_s[t] = hh;
    sq_s[t] = sqrtf(hh);
  }

  float ymine = 0.1f;
  if (lane < 3) ymine = fminf(fmaxf(ts[b * 1536 + lane], 0.01f), 10.f);
  y_s[w][lane] = ymine;
  if (w == 0) out[(long)b * 32768 + lane] = ymine;
  if (w == 1) outB[((long)b * 512) * 64 + lane] = f2b(ymine);

  const long nofs = (long)b * 64 + lane;
  float nz0 = noise[nofs];
  float nz1 = noise[4096 + nofs];
  float nz2 = noise[2 * 4096 + nofs];
  float nz3 = noise[3 * 4096 + nofs];
  __syncthreads();

  for (int i = 0; i < 511; i++) {
    const int buf = i & 1;
    const float tl = tl_s[i];
    const float hh = hs_s[i];
    const float sq = sq_s[i];

    // noise shift-register (compile-time slots)
    const float nz = nz0;
    nz0 = nz1; nz1 = nz2; nz2 = nz3;
    if (i + 4 < 511) nz3 = noise[(long)(i + 4) * 4096 + nofs];

    // ---- stage A: 2 lanes/out, 32 MACs, own y copy (broadcast reads) ----
    float a0 = 0.f, a1 = 0.f, a2 = 0.f, a3 = 0.f;
#pragma unroll
    for (int g = 0; g < 8; g++) {
      float4 yv = *(const float4*)&y_s[w][hA * 32 + g * 4];
      a0 += yv.x * wA[g * 4 + 0];
      a1 += yv.y * wA[g * 4 + 1];
      a2 += yv.z * wA[g * 4 + 2];
      a3 += yv.w * wA[g * 4 + 3];
    }
    float p1 = (a0 + a1) + (a2 + a3);
    p1 += hA ? (tl * wAt) : bA;
    p1 = dpp_xor1_add(p1);                // VALU pair-combine (no LDS pipe)
    float h1v = fast_tanh(p1);
    if (hA == 0) h1seg[w][lane >> 1] = h1v;
    // intra-wave handoff: no barrier

    // ---- stage B partial: 32 MACs over own segment (broadcast reads) ----
    float c0 = 0.f, c1 = 0.f, c2 = 0.f, c3 = 0.f;
#pragma unroll
    for (int g = 0; g < 8; g++) {
      float4 hv = *(const float4*)&h1seg[w][g * 4];
      c0 += hv.x * wB[g * 4 + 0];
      c1 += hv.y * wB[g * 4 + 1];
      c2 += hv.z * wB[g * 4 + 2];
      c3 += hv.w * wB[g * 4 + 3];
    }
    float psum = (c0 + c1) + (c2 + c3);
    if (drift) pd[buf][wseg][lane] = psum;
    else       pg[buf][wseg][lane] = psum;

    barrier_lds();                        // the ONE barrier per step

    // ---- reduce (redundant per wave): h2[lane], gc[lane] ----
    float sd = ((pd[buf][0][lane] + pd[buf][1][lane]) +
                (pd[buf][2][lane] + pd[buf][3][lane])) + bBd;
    float h2v = fast_tanh(sd);
    float sg = ((pg[buf][0][lane] + pg[buf][1][lane]) +
                (pg[buf][2][lane] + pg[buf][3][lane])) + bBg;
    float gc = fmaxf(sg, 0.f) + __logf(1.f + __expf(-fabsf(sg))) + mind;
    h2c[w][lane] = h2v;
    // intra-wave handoff: no barrier

    // ---- stage C (redundant per wave): 64 MACs, broadcast reads ----
    float d0 = 0.f, d1 = 0.f, d2 = 0.f, d3 = 0.f;
#pragma unroll
    for (int g = 0; g < 16; g++) {
      float4 hv = *(const float4*)&h2c[w][g * 4];
      d0 += hv.x * wC[g * 4 + 0];
      d1 += hv.y * wC[g * 4 + 1];
      d2 += hv.z * wC[g * 4 + 2];
      d3 += hv.w * wC[g * 4 + 3];
    }
    float dc = fminf(fmaxf((d0 + d1) + (d2 + d3) + bC, -maxd), maxd);

    // ---- y update (redundant per wave, own copy) ----
    float yo = ymine;
    float yn = yo + dc * yo * hh + gc * fminf(fmaxf(yo, -10.f), 10.f) * nz * sq;
    yn = fminf(fmaxf(yn, 0.01f), 10.f);
    y_s[w][lane] = yn;
    ymine = yn;
    if (w == 0) out[(long)b * 32768 + (i + 1) * 64 + lane] = yn;
    if (w == 1) outB[((long)b * 512 + i + 1) * 64 + lane] = f2b(yn);
  }
}

// ---------------------------------------------------------------------------
__global__ __launch_bounds__(256) void prep_weights(
    const float* __restrict__ in_W, const float* __restrict__ Wq,
    const float* __restrict__ Wk, const float* __restrict__ Wv,
    const float* __restrict__ Wo, const float* __restrict__ fW1,
    const float* __restrict__ fW2,
    u16* __restrict__ inWt, u16* __restrict__ qkvWt, u16* __restrict__ Wot,
    u16* __restrict__ fW1t, u16* __restrict__ fW2t) {
  const int z = blockIdx.z, layer = blockIdx.y, tile = blockIdx.x;
  const float* src; u16* dst; int R, C, nl;
  switch (z) {
    case 0: src = in_W; dst = inWt; R = 64; C = 128; nl = 1; break;
    case 1: src = Wq + layer * 16384; dst = qkvWt + layer * 49152; R = 128; C = 128; nl = 4; break;
    case 2: src = Wk + layer * 16384; dst = qkvWt + layer * 49152 + 16384; R = 128; C = 128; nl = 4; break;
    case 3: src = Wv + layer * 16384; dst = qkvWt + layer * 49152 + 32768; R = 128; C = 128; nl = 4; break;
    case 4: src = Wo + layer * 16384; dst = Wot + layer * 16384; R = 128; C = 128; nl = 4; break;
    case 5: src = fW1 + layer * 65536; dst = fW1t + layer * 65536; R = 128; C = 512; nl = 4; break;
    default: src = fW2 + layer * 65536; dst = fW2t + layer * 65536; R = 512; C = 128; nl = 4; break;
  }
  const int nt = (R / 32) * (C / 32);
  if (layer >= nl || tile >= nt) return;
  const int tpr = C / 32;
  const int r0 = (tile / tpr) * 32, c0 = (tile % tpr) * 32;
  __shared__ float tl[32][33];
  const int tx = threadIdx.x & 31, ty = threadIdx.x >> 5;
#pragma unroll
  for (int p = 0; p < 4; p++)
    tl[ty + 8 * p][tx] = src[(long)(r0 + ty + 8 * p) * C + c0 + tx];
  __syncthreads();
#pragma unroll
  for (int p = 0; p < 4; p++)
    dst[(long)(c0 + ty + 8 * p) * R + r0 + tx] = f2b(tl[tx][ty + 8 * p]);
}

// ---------------------------------------------------------------------------
// bf16 MFMA GEMM (bf16 out). Used once for x = sde @ in_W.
// ---------------------------------------------------------------------------
__global__ __launch_bounds__(256) void mfma_gemm(
    const u16* __restrict__ A, const u16* __restrict__ Bt,
    const float* __restrict__ bias, u16* __restrict__ outB, int K, int N) {
  __shared__ u16 As[128 * 40];
  __shared__ u16 Bs[64 * 40];
  const int t = threadIdx.x;
  const int nb = blockIdx.x * 64;
  const long mb = (long)blockIdx.y * 128;
  const int lane = t & 63, wave = t >> 6;
  const int wm = (wave >> 1) * 64, wn = (wave & 1) * 32;
  const int fr = lane & 15, quad = lane >> 4;

  f32x4 zero = {0.f, 0.f, 0.f, 0.f};
  f32x4 acc[4][2];
#pragma unroll
  for (int mi = 0; mi < 4; mi++)
#pragma unroll
    for (int ni = 0; ni < 2; ni++) acc[mi][ni] = zero;

  for (int k0 = 0; k0 < K; k0 += 32) {
#pragma unroll
    for (int p = 0; p < 2; p++) {
      int idx = t + p * 256, row = idx >> 2, seg = idx & 3;
      int4 v = *(const int4*)&A[(mb + row) * K + k0 + seg * 8];
      *(int4*)&As[row * 40 + seg * 8] = v;
    }
    {
      int row = t >> 2, seg = t & 3;
      int4 v = *(const int4*)&Bt[(long)(nb + row) * K + k0 + seg * 8];
      *(int4*)&Bs[row * 40 + seg * 8] = v;
    }
    __syncthreads();
    bf16x8 af[4], bfr[2];
#pragma unroll
    for (int mi = 0; mi < 4; mi++)
      af[mi] = *(const bf16x8*)&As[(wm + mi * 16 + fr) * 40 + quad * 8];
#pragma unroll
    for (int ni = 0; ni < 2; ni++)
      bfr[ni] = *(const bf16x8*)&Bs[(wn + ni * 16 + fr) * 40 + quad * 8];
#pragma unroll
    for (int mi = 0; mi < 4; mi++)
#pragma unroll
      for (int ni = 0; ni < 2; ni++)
        acc[mi][ni] = __builtin_amdgcn_mfma_f32_16x16x32_bf16(
            af[mi], bfr[ni], acc[mi][ni], 0, 0, 0);
    __syncthreads();
  }

#pragma unroll
  for (int mi = 0; mi < 4; mi++)
#pragma unroll
    for (int ni = 0; ni < 2; ni++) {
      int col = nb + wn + ni * 16 + fr;
      float bv = bias[col];
#pragma unroll
      for (int r = 0; r < 4; r++) {
        long row = mb + wm + mi * 16 + quad * 4 + r;
        outB[row * N + col] = f2b(acc[mi][ni][r] + bv);
      }
    }
}

// ---------------------------------------------------------------------------
// layer_tail (round-9 v1, verified): x <- LN2( x' + relu(x'@W1+b1)@W2+b2 ),
// x' = LN1(x + o@Wo+bo). 512 blocks x 512 thr, 1 block/CU (~89 KB LDS).
// All B-operands streamed from L2. x' kept in registers for the FFN2
// residual; staged once in LDS for the FFN1 A-fragments. LN stats via DPP
// red16 + owner-lane pass. NOTE: do NOT cap VGPRs via launch_bounds —
// both spill experiments (r1, r10) regressed badly.
// ---------------------------------------------------------------------------
__global__ __launch_bounds__(512, 1) void layer_tail(
    const u16* __restrict__ ob, const u16* __restrict__ Wot,
    const float* __restrict__ bo, const float* __restrict__ ln1s,
    const float* __restrict__ ln1b, const u16* __restrict__ W1t,
    const float* __restrict__ fb1, const u16* __restrict__ W2t,
    const float* __restrict__ fb2, const float* __restrict__ ln2s,
    const float* __restrict__ ln2b, u16* __restrict__ xb) {
  __shared__ u16 As[64 * 136];        // attn-out tile, then x' tile
  __shared__ u16 Hs[64 * 520];        // hidden tile
  __shared__ float s1[64][8], s2[64][8];
  __shared__ float mst[64][2];
  const int t = threadIdx.x;
  const long mb = (long)blockIdx.x * 64;
  const int w = t >> 6, lane = t & 63;
  const int fr = lane & 15, quad = lane >> 4;
  const int col = w * 16 + fr;        // this thread's output column
  const f32x4 z4 = {0.f, 0.f, 0.f, 0.f};

  // ---- stage attn-out tile 64x128 ----
#pragma unroll
  for (int p = 0; p < 2; p++) {
    int c = t + p * 512;
    int row = c >> 4, sub = c & 15;
    *(int4*)&As[row * 136 + sub * 8] =
        *(const int4*)&ob[(mb + row) * DD + sub * 8];
  }
  __syncthreads();

  // ---- attn-out projection: o @ Wo (K=128), B streamed from L2 ----
  bf16x8 af[4][4];
#pragma unroll
  for (int m = 0; m < 4; m++)
#pragma unroll
    for (int c = 0; c < 4; c++)
      af[m][c] = *(const bf16x8*)&As[(m * 16 + fr) * 136 + c * 32 + quad * 8];

  f32x4 acc[4] = {z4, z4, z4, z4};
#pragma unroll
  for (int kc = 0; kc < 4; kc++) {
    bf16x8 bfr = *(const bf16x8*)&Wot[col * 128 + kc * 32 + quad * 8];
#pragma unroll
    for (int m = 0; m < 4; m++)
      acc[m] = __builtin_amdgcn_mfma_f32_16x16x32_bf16(af[m][kc], bfr,
                                                       acc[m], 0, 0, 0);
  }

  // ---- residual + LN1 partials ----
  const float bov = bo[col], g1 = ln1s[col], be1 = ln1b[col];
  float vv[4][4];
#pragma unroll
  for (int m = 0; m < 4; m++)
#pragma unroll
    for (int r = 0; r < 4; r++) {
      int row = m * 16 + quad * 4 + r;
      float v = acc[m][r] + bov + b2f(xb[(mb + row) * DD + col]);
      vv[m][r] = v;
      float s = red16(v);
      float ss = red16(v * v);
      if (fr == 0) { s1[row][w] = s; s2[row][w] = ss; }
    }
  __syncthreads();
  {
    int row = lane;
    float4 a = *(const float4*)&s1[row][0];
    float4 bq4 = *(const float4*)&s1[row][4];
    float sumv = ((a.x + a.y) + (a.z + a.w)) +
                 ((bq4.x + bq4.y) + (bq4.z + bq4.w));
    float4 cq = *(const float4*)&s2[row][0];
    float4 dq = *(const float4*)&s2[row][4];
    float sumsq = ((cq.x + cq.y) + (cq.z + cq.w)) +
                  ((dq.x + dq.y) + (dq.z + dq.w));
    float mean = sumv * (1.f / 128.f);
    float var = sumsq * (1.f / 128.f) - mean * mean;
    mst[row][0] = mean;
    mst[row][1] = rsqrtf(var + 1e-5f);
  }
  __syncthreads();

  // ---- x' = LN1(...): keep in regs (FFN2 residual) + stage in LDS ----
  float xr[4][4];
#pragma unroll
  for (int m = 0; m < 4; m++)
#pragma unroll
    for (int r = 0; r < 4; r++) {
      int row = m * 16 + quad * 4 + r;
      float xv = (vv[m][r] - mst[row][0]) * mst[row][1] * g1 + be1;
      xr[m][r] = xv;
      As[row * 136 + col] = f2b(xv);
    }
  __syncthreads();

  // ---- FFN1: A-frags from x', W1 streamed; wave covers 4 col-tiles ----
  bf16x8 af2[4][4];
#pragma unroll
  for (int m = 0; m < 4; m++)
#pragma unroll
    for (int c = 0; c < 4; c++)
      af2[m][c] = *(const bf16x8*)&As[(m * 16 + fr) * 136 + c * 32 + quad * 8];

#pragma unroll
  for (int nn = 0; nn < 4; nn++) {
    const int nt = w * 4 + nn;
    bf16x8 bfr[4];
#pragma unroll
    for (int c = 0; c < 4; c++)
      bfr[c] = *(const bf16x8*)&W1t[(nt * 16 + fr) * 128 + c * 32 + quad * 8];
    f32x4 a1[4] = {z4, z4, z4, z4};
#pragma unroll
    for (int c = 0; c < 4; c++)
#pragma unroll
      for (int m = 0; m < 4; m++)
        a1[m] = __builtin_amdgcn_mfma_f32_16x16x32_bf16(af2[m][c], bfr[c],
                                                        a1[m], 0, 0, 0);
    const float bv = fb1[nt * 16 + fr];
#pragma unroll
    for (int m = 0; m < 4; m++)
#pragma unroll
      for (int r = 0; r < 4; r++)
        Hs[(m * 16 + quad * 4 + r) * 520 + nt * 16 + fr] =
            f2b(fmaxf(a1[m][r] + bv, 0.f));
  }
  __syncthreads();

  // ---- FFN2: K=512, W2 streamed; wave covers out cols w*16.. ----
  f32x4 acc2[4] = {z4, z4, z4, z4};
#pragma unroll
  for (int kc = 0; kc < 16; kc++) {
    bf16x8 bfr2 = *(const bf16x8*)&W2t[col * 512 + kc * 32 + quad * 8];
    bf16x8 a2[4];
#pragma unroll
    for (int m = 0; m < 4; m++)
      a2[m] = *(const bf16x8*)&Hs[(m * 16 + fr) * 520 + kc * 32 + quad * 8];
#pragma unroll
    for (int m = 0; m < 4; m++)
      acc2[m] = __builtin_amdgcn_mfma_f32_16x16x32_bf16(a2[m], bfr2,
                                                        acc2[m], 0, 0, 0);
  }

  // ---- residual (from regs!) + LN2 ----
  const float bv2 = fb2[col], g2 = ln2s[col], be2 = ln2b[col];
#pragma unroll
  for (int m = 0; m < 4; m++)
#pragma unroll
    for (int r = 0; r < 4; r++) {
      int row = m * 16 + quad * 4 + r;
      float v = acc2[m][r] + bv2 + xr[m][r];
      vv[m][r] = v;
      float s = red16(v);
      float ss = red16(v * v);
      if (fr == 0) { s1[row][w] = s; s2[row][w] = ss; }
    }
  __syncthreads();
  {
    int row = lane;
    float4 a = *(const float4*)&s1[row][0];
    float4 bq4 = *(const float4*)&s1[row][4];
    float sumv = ((a.x + a.y) + (a.z + a.w)) +
                 ((bq4.x + bq4.y) + (bq4.z + bq4.w));
    float4 cq = *(const float4*)&s2[row][0];
    float4 dq = *(const float4*)&s2[row][4];
    float sumsq = ((cq.x + cq.y) + (cq.z + cq.w)) +
                  ((dq.x + dq.y) + (dq.z + dq.w));
    float mean = sumv * (1.f / 128.f);
    float var = sumsq * (1.f / 128.f) - mean * mean;
    mst[row][0] = mean;
    mst[row][1] = rsqrtf(var + 1e-5f);
  }
  __syncthreads();

#pragma unroll
  for (int m = 0; m < 4; m++)
#pragma unroll
    for (int r = 0; r < 4; r++) {
      int row = m * 16 + quad * 4 + r;
      xb[(mb + row) * DD + col] =
          f2b((vv[m][r] - mst[row][0]) * mst[row][1] * g2 + be2);
    }
}

// ---------------------------------------------------------------------------
// Fused QKV-projection + flash attention (round-9 v4, verified champion).
// One block per (b,h), 512 blocks, 2 blocks/CU (64.3 KB LDS).
// V at permuted LDS slots tau(s) = ((s&12)<<1)|(s&3)|((s&16)>>2) so the
// S^T C-layout's native packed words ARE the PV B-frag (no ds_bpermute).
// No-max exp2 softmax (Q pre-scaled by 0.25*log2e), cvt_pk P-packing,
// l-reduction hoisted out of the kt loop. NOTE: v5 (Qs->per-wave scratch +
// launch_bounds(256,3)) regressed +128us — VGPR-cap spills; do not re-try.
// ---------------------------------------------------------------------------
__global__ __launch_bounds__(256, 2) void qkv_attn(
    const u16* __restrict__ xb, const u16* __restrict__ qkvW,
    const float* __restrict__ bq, const float* __restrict__ bk,
    const float* __restrict__ bv, u16* __restrict__ Og) {
  const int bh = blockIdx.x;
  const int b = bh >> 3, h = bh & 7;
  __shared__ u16 Ks[512 * 24];     // [key][d]  (24 KB)
  __shared__ u16 Vt[16 * 520];     // [d][key-slot]  (16.3 KB)
  __shared__ u16 Qs[512 * 24];     // [q][d]    (24 KB)
  const int t = threadIdx.x;
  const int w = t >> 6, lane = t & 63;
  const int fr = lane & 15, quad = lane >> 4;
  const long obase = ((long)b * SS) * DD + h * 16;
  const u16* xrow = xb + (long)b * SS * DD;

  // ---- head weight B-frags (register-resident) ----
  const u16* Wq_h = qkvW + (h * 16) * 128;
  const u16* Wk_h = qkvW + 16384 + (h * 16) * 128;
  const u16* Wv_h = qkvW + 32768 + (h * 16) * 128;
  bf16x8 wqf[4], wkf[4], wvf[4];
#pragma unroll
  for (int c = 0; c < 4; c++) {
    wqf[c] = *(const bf16x8*)&Wq_h[fr * 128 + c * 32 + quad * 8];
    wkf[c] = *(const bf16x8*)&Wk_h[fr * 128 + c * 32 + quad * 8];
    wvf[c] = *(const bf16x8*)&Wv_h[fr * 128 + c * 32 + quad * 8];
  }
  const float bqv = bq[h * 16 + fr];
  const float bkv = bk[h * 16 + fr];
  const float bvv = bv[h * 16 + fr];
  const f32x4 z4 = {0.f, 0.f, 0.f, 0.f};
  const float qscale = 0.25f * 1.4426950408889634f;  // 1/sqrt(16) * log2(e)

  // ---- project Q/K/V for this head into LDS ----
  for (int tile = w; tile < 32; tile += 4) {
    const int t0 = tile * 16;
    bf16x8 af[4];
#pragma unroll
    for (int c = 0; c < 4; c++)
      af[c] = *(const bf16x8*)&xrow[(t0 + fr) * 128 + c * 32 + quad * 8];
    f32x4 qa = z4, ka = z4, va = z4;
#pragma unroll
    for (int c = 0; c < 4; c++) {
      qa = __builtin_amdgcn_mfma_f32_16x16x32_bf16(af[c], wqf[c], qa, 0, 0, 0);
      ka = __builtin_amdgcn_mfma_f32_16x16x32_bf16(af[c], wkf[c], ka, 0, 0, 0);
      va = __builtin_amdgcn_mfma_f32_16x16x32_bf16(af[c], wvf[c], va, 0, 0, 0);
    }
    // C-layout: lane holds (d = fr, row = t0 + quad*4 + r)
#pragma unroll
    for (int r = 0; r < 4; r++) {
      int row = t0 + quad * 4 + r;
      Qs[row * 24 + fr] = f2b((qa[r] + bqv) * qscale);
      Ks[row * 24 + fr] = f2b(ka[r] + bkv);
    }
    // V: permuted slots (tau), 4 consecutive rows -> one b64 write.
    {
      const int t0q = t0 + quad * 4;
      const int r40 = t0q & 31;
      const int vbase = (t0q & ~31) + ((r40 & 12) << 1) + ((r40 & 16) >> 2);
      uint2 vvv;
      vvv.x = cvt_pk_bf16(va[0] + bvv, va[1] + bvv);
      vvv.y = cvt_pk_bf16(va[2] + bvv, va[3] + bvv);
      *(uint2*)&Vt[fr * 520 + vbase] = vvv;
    }
  }
  __syncthreads();

  // ---- flash attention (S^T orientation, no-max exp2 softmax) ----
  for (int qt = w; qt < 32; qt += 4) {
    const int q0 = qt * 16;
    bf16x8 qf = {0, 0, 0, 0, 0, 0, 0, 0};
    if (quad < 2)
      qf = *(const bf16x8*)&Qs[(q0 + fr) * 24 + quad * 8];
    f32x4 oacc = {0.f, 0.f, 0.f, 0.f};
    float rsacc = 0.f;                 // per-lane partial l (reduced once)

    for (int kt = 0; kt < 16; kt++) {
      const int k0 = kt * 32;
      bf16x8 kf0 = {0, 0, 0, 0, 0, 0, 0, 0};
      bf16x8 kf1 = {0, 0, 0, 0, 0, 0, 0, 0};
      if (quad < 2) {
        kf0 = *(const bf16x8*)&Ks[(k0 + fr) * 24 + quad * 8];
        kf1 = *(const bf16x8*)&Ks[(k0 + 16 + fr) * 24 + quad * 8];
      }
      f32x4 slo = __builtin_amdgcn_mfma_f32_16x16x32_bf16(kf0, qf, z4, 0, 0, 0);
      f32x4 shi = __builtin_amdgcn_mfma_f32_16x16x32_bf16(kf1, qf, z4, 0, 0, 0);
      float p[8];
#pragma unroll
      for (int r = 0; r < 4; r++) {
        p[r] = __builtin_amdgcn_exp2f(slo[r]);
        p[4 + r] = __builtin_amdgcn_exp2f(shi[r]);
      }
      rsacc += ((p[0] + p[1]) + (p[2] + p[3])) +
               ((p[4] + p[5]) + (p[6] + p[7]));

      // native packed P words ARE the B-frag (V slots pre-permuted)
      union { unsigned i[4]; bf16x8 v; } pu;
      pu.i[0] = cvt_pk_bf16(p[0], p[1]);
      pu.i[1] = cvt_pk_bf16(p[2], p[3]);
      pu.i[2] = cvt_pk_bf16(p[4], p[5]);
      pu.i[3] = cvt_pk_bf16(p[6], p[7]);
      bf16x8 vf = *(const bf16x8*)&Vt[fr * 520 + k0 + quad * 8];
      oacc = __builtin_amdgcn_mfma_f32_16x16x32_bf16(vf, pu.v, oacc, 0, 0, 0);
    }

    float lrun = rsacc;
    lrun += __shfl_xor(lrun, 16);
    lrun += __shfl_xor(lrun, 32);
    float inv = __fdividef(1.f, lrun);
    uint2 o;
    o.x = cvt_pk_bf16(oacc[0] * inv, oacc[1] * inv);
    o.y = cvt_pk_bf16(oacc[2] * inv, oacc[3] * inv);
    *(uint2*)&Og[obase + (long)(q0 + fr) * DD + quad * 4] = o;
  }
}

// ---------------------------------------------------------------------------
// Fused mean-pool + classifier head (one launch, no bp round-trip).
// ---------------------------------------------------------------------------
__global__ __launch_bounds__(512) void pool_cls(
    const u16* __restrict__ X, const float* __restrict__ W1,
    const float* __restrict__ b1, const float* __restrict__ W2,
    const float* __restrict__ b2, float* __restrict__ L) {
  const int b = blockIdx.x, t = threadIdx.x;
  const int c = t & 127, sg = t >> 7;       // 4 s-groups
  __shared__ float red[4][128];
  __shared__ float sp[128];
  __shared__ float sh[64];
  float acc = 0.f;
  for (int s = sg; s < SS; s += 4)
    acc += b2f(X[((long)b * SS + s) * DD + c]);
  red[sg][c] = acc;
  __syncthreads();
  if (t < 128)
    sp[t] = (red[0][t] + red[1][t] + red[2][t] + red[3][t]) * (1.f / 512.f);
  __syncthreads();
  if (t < 64) {
    float a2 = b1[t];
    for (int k = 0; k < 128; k++) a2 += sp[k] * W1[k * 64 + t];
    sh[t] = fmaxf(a2, 0.f);
  }
  __syncthreads();
  if (t < 5) {
    float a3 = b2[t];
    for (int k = 0; k < 64; k++) a3 += sh[k] * W2[k * 5 + t];
    L[b * 5 + t] = a3;
  }
}

// ---------------------------------------------------------------------------
extern "C" void kernel_launch(void* const* d_in, const int* in_sizes, int n_in,
                              void* d_out, int out_size, void* d_ws, size_t ws_size,
                              hipStream_t stream) {
  const float* ts    = (const float*)d_in[0];
  const float* noise = (const float*)d_in[2];
  const float* dW1   = (const float*)d_in[3];
  const float* db1   = (const float*)d_in[4];
  const float* dW2   = (const float*)d_in[5];
  const float* db2   = (const float*)d_in[6];
  const float* dW3   = (const float*)d_in[7];
  const float* db3   = (const float*)d_in[8];
  const float* gW1   = (const float*)d_in[9];
  const float* gb1   = (const float*)d_in[10];
  const float* gW2   = (const float*)d_in[11];
  const float* gb2   = (const float*)d_in[12];
  const float* mind  = (const float*)d_in[13];
  const float* maxd  = (const float*)d_in[14];
  const float* in_W  = (const float*)d_in[15];
  const float* in_b  = (const float*)d_in[16];
  const float* Wq    = (const float*)d_in[17];
  const float* bq    = (const float*)d_in[18];
  const float* Wk    = (const float*)d_in[19];
  const float* bk    = (const float*)d_in[20];
  const float* Wv    = (const float*)d_in[21];
  const float* bv    = (const float*)d_in[22];
  const float* Wo    = (const float*)d_in[23];
  const float* bo    = (const float*)d_in[24];
  const float* ln1s  = (const float*)d_in[25];
  const float* ln1b  = (const float*)d_in[26];
  const float* fW1   = (const float*)d_in[27];
  const float* fb1   = (const float*)d_in[28];
  const float* fW2   = (const float*)d_in[29];
  const float* fb2   = (const float*)d_in[30];
  const float* ln2s  = (const float*)d_in[31];
  const float* ln2b  = (const float*)d_in[32];
  const float* cW1   = (const float*)d_in[33];
  const float* cb1   = (const float*)d_in[34];
  const float* cW2   = (const float*)d_in[35];
  const float* cb2   = (const float*)d_in[36];

  float* logits = (float*)d_out;
  float* sde    = logits + BB * 5;

  // Workspace (all-bf16 residual stream):
  char* W = (char*)d_ws;
  u16*  bxb    = (u16*)(W);                   //  8 MB bf16 x
  u16*  bob    = (u16*)(W + (40u << 20));     //  8 MB bf16 attn out
  u16*  bsb    = (u16*)(W + (48u << 20));     //  4 MB bf16 sde feats
  u16*  wts    = (u16*)(W + (52u << 20));     // ~1.5 MB bf16 weights

  u16* inWt  = wts;                 // [128][64]
  u16* qkvWt = inWt + 8192;         // [4][3][128][128]
  u16* Wot   = qkvWt + 196608;      // [4][128][128]
  u16* fW1t  = Wot + 65536;         // [4][512][128]
  u16* fW2t  = fW1t + 262144;       // [4][128][512]

  prep_weights<<<dim3(64, 4, 7), 256, 0, stream>>>(in_W, Wq, Wk, Wv, Wo, fW1, fW2,
                                                   inWt, qkvWt, Wot, fW1t, fW2t);

  sde_kernel<<<64, 512, 0, stream>>>(ts, noise, dW1, db1, dW2, db2, dW3, db3,
                                     gW1, gb1, gW2, gb2, mind, maxd, sde, bsb);

  // x = sde @ in_W + in_b  (bf16)
  mfma_gemm<<<dim3(2, 256), 256, 0, stream>>>(bsb, inWt, in_b, bxb, 64, 128);

  for (int l = 0; l < 4; l++) {
    qkv_attn<<<BB * NHD, 256, 0, stream>>>(bxb, qkvWt + l * 49152,
                                           bq + l * DD, bk + l * DD, bv + l * DD,
                                           bob);
    layer_tail<<<512, 512, 0, stream>>>(bob, Wot + l * 16384, bo + l * DD,
                                        ln1s + l * DD, ln1b + l * DD,
                                        fW1t + l * 65536, fb1 + l * 512,
                                        fW2t + l * 65536, fb2 + l * DD,
                                        ln2s + l * DD, ln2b + l * DD, bxb);
  }

  pool_cls<<<BB, 512, 0, stream>>>(bxb, cW1, cb1, cW2, cb2, logits);
}

// Round 14
// 1017.450 us; speedup vs baseline: 1.1554x; 1.0264x over previous
//
#include <hip/hip_runtime.h>
#include <hip/hip_bf16.h>
#include <math.h>

#define BB 64
#define SS 512
#define HH 64
#define DD 128
#define NHD 8
#define ROWS (BB*SS)   // 32768

typedef unsigned short u16;
typedef __attribute__((ext_vector_type(8))) short bf16x8;
typedef __attribute__((ext_vector_type(4))) float f32x4;

__device__ __forceinline__ u16 f2b(float f) {
  union { float f; unsigned u; } x; x.f = f;
  unsigned r = x.u + 0x7fffu + ((x.u >> 16) & 1u);
  return (u16)(r >> 16);
}

__device__ __forceinline__ float b2f(u16 u) {
  return __uint_as_float(((unsigned)u) << 16);
}

// packed bf16 convert (RNE), 1 instruction for 2 values.
__device__ __forceinline__ unsigned cvt_pk_bf16(float lo, float hi) {
  unsigned r;
  asm("v_cvt_pk_bf16_f32 %0, %1, %2" : "=v"(r) : "v"(lo), "v"(hi));
  return r;
}

__device__ __forceinline__ float fast_tanh(float x) {
  float ax = fminf(fabsf(x), 15.f);
  float e = __expf(2.f * ax);
  float r = 1.f - __fdividef(2.f, e + 1.f);
  return copysignf(r, x);
}

__device__ __forceinline__ void barrier_lds() {
  __builtin_amdgcn_s_waitcnt(0xC07F);   // lgkmcnt(0) only
  __builtin_amdgcn_s_barrier();
}

// pair-combine via DPP (VALU, not LDS pipe): add value of lane^1
__device__ __forceinline__ float dpp_xor1_add(float x) {
  int pi = __float_as_int(x);
  int po = __builtin_amdgcn_update_dpp(0, pi, 0xB1 /*quad_perm [1,0,3,2]*/,
                                       0xF, 0xF, true);
  return x + __int_as_float(po);
}

template <int CTRL>
__device__ __forceinline__ float dpp_add(float x) {
  int po = __builtin_amdgcn_update_dpp(0, __float_as_int(x), CTRL, 0xF, 0xF, true);
  return x + __int_as_float(po);
}
// sum across each 16-lane group, all on the VALU pipe
__device__ __forceinline__ float red16(float x) {
  x = dpp_add<0xB1>(x);    // quad_perm xor1
  x = dpp_add<0x4E>(x);    // quad_perm xor2
  x = dpp_add<0x141>(x);   // row_half_mirror (combines 4-groups)
  x = dpp_add<0x140>(x);   // row_mirror (combines 8-halves)
  return x;
}

// ---------------------------------------------------------------------------
// SDE scan v10 (verified 577 us): 8 waves (0-3 drift, 4-7 diffusion), ONE
// barrier per step, K-segmented stage B, redundant reduce + LDS-staged
// stage C per wave, per-wave private y. Stable local optimum — frozen.
// ---------------------------------------------------------------------------
__global__ __attribute__((amdgpu_flat_work_group_size(512, 512)))
__attribute__((amdgpu_waves_per_eu(2, 2))) void sde_kernel(
    const float* __restrict__ ts, const float* __restrict__ noise,
    const float* __restrict__ dW1, const float* __restrict__ db1,
    const float* __restrict__ dW2, const float* __restrict__ db2,
    const float* __restrict__ dW3, const float* __restrict__ db3,
    const float* __restrict__ gW1, const float* __restrict__ gb1,
    const float* __restrict__ gW2, const float* __restrict__ gb2,
    const float* __restrict__ pmind, const float* __restrict__ pmaxd,
    float* __restrict__ out, u16* __restrict__ outB) {
  const int b = blockIdx.x, t = threadIdx.x;
  const int w = t >> 6, lane = t & 63;
  const int drift = (w < 4) ? 1 : 0;
  const int wseg = w & 3;                 // K-segment index 0..3

  __shared__ float y_s[8][64];            // per-wave private y copy
  __shared__ float h1seg[8][32];          // per-wave A output segment
  __shared__ float h2c[8][64];            // per-wave private h2 copy
  __shared__ float pd[2][4][64];          // drift B partials (parity dbuf)
  __shared__ float pg[2][4][64];          // diffusion B partials
  __shared__ float tl_s[512], hs_s[512], sq_s[512];

  const float mind = fabsf(pmind[0]);
  const float maxd = fabsf(pmaxd[0]);

  // ---- stage A weights: out col = wseg*32 + (lane>>1), hA = K-half ----
  const int colA = wseg * 32 + (lane >> 1);
  const int hA = lane & 1;
  const float* W1 = drift ? dW1 : gW1;
  float wA[32];
#pragma unroll
  for (int k = 0; k < 32; k++) wA[k] = W1[(hA * 32 + k) * 128 + colA];
  const float wAt = W1[64 * 128 + colA];
  const float bA = (drift ? db1 : gb1)[colA];

  // ---- stage B partial weights: out col = lane, K rows wseg*32.. ----
  const float* W2 = drift ? dW2 : gW2;
  float wB[32];
#pragma unroll
  for (int k = 0; k < 32; k++) wB[k] = W2[(wseg * 32 + k) * 64 + lane];
  const float bBd = db2[lane], bBg = gb2[lane];

  // ---- stage C weights (every wave, redundant): out col = lane ----
  float wC[64];
#pragma unroll
  for (int k = 0; k < 64; k++) wC[k] = dW3[k * 64 + lane];
  const float bC = db3[lane];

  // ---- prologue ----
  tl_s[t & 511] = ts[(t & 511) * 3];
  __syncthreads();
  if (t < 511) {
    float hh = tl_s[t + 1] - tl_s[t];
    hs_s[t] = hh;
    sq_s[t] = sqrtf(hh);
  }

  float ymine = 0.1f;
  if (lane < 3) ymine = fminf(fmaxf(ts[b * 1536 + lane], 0.01f), 10.f);
  y_s[w][lane] = ymine;
  if (w == 0) out[(long)b * 32768 + lane] = ymine;
  if (w == 1) outB[((long)b * 512) * 64 + lane] = f2b(ymine);

  const long nofs = (long)b * 64 + lane;
  float nz0 = noise[nofs];
  float nz1 = noise[4096 + nofs];
  float nz2 = noise[2 * 4096 + nofs];
  float nz3 = noise[3 * 4096 + nofs];
  __syncthreads();

  for (int i = 0; i < 511; i++) {
    const int buf = i & 1;
    const float tl = tl_s[i];
    const float hh = hs_s[i];
    const float sq = sq_s[i];

    // noise shift-register (compile-time slots)
    const float nz = nz0;
    nz0 = nz1; nz1 = nz2; nz2 = nz3;
    if (i + 4 < 511) nz3 = noise[(long)(i + 4) * 4096 + nofs];

    // ---- stage A: 2 lanes/out, 32 MACs, own y copy (broadcast reads) ----
    float a0 = 0.f, a1 = 0.f, a2 = 0.f, a3 = 0.f;
#pragma unroll
    for (int g = 0; g < 8; g++) {
      float4 yv = *(const float4*)&y_s[w][hA * 32 + g * 4];
      a0 += yv.x * wA[g * 4 + 0];
      a1 += yv.y * wA[g * 4 + 1];
      a2 += yv.z * wA[g * 4 + 2];
      a3 += yv.w * wA[g * 4 + 3];
    }
    float p1 = (a0 + a1) + (a2 + a3);
    p1 += hA ? (tl * wAt) : bA;
    p1 = dpp_xor1_add(p1);                // VALU pair-combine (no LDS pipe)
    float h1v = fast_tanh(p1);
    if (hA == 0) h1seg[w][lane >> 1] = h1v;
    // intra-wave handoff: no barrier

    // ---- stage B partial: 32 MACs over own segment (broadcast reads) ----
    float c0 = 0.f, c1 = 0.f, c2 = 0.f, c3 = 0.f;
#pragma unroll
    for (int g = 0; g < 8; g++) {
      float4 hv = *(const float4*)&h1seg[w][g * 4];
      c0 += hv.x * wB[g * 4 + 0];
      c1 += hv.y * wB[g * 4 + 1];
      c2 += hv.z * wB[g * 4 + 2];
      c3 += hv.w * wB[g * 4 + 3];
    }
    float psum = (c0 + c1) + (c2 + c3);
    if (drift) pd[buf][wseg][lane] = psum;
    else       pg[buf][wseg][lane] = psum;

    barrier_lds();                        // the ONE barrier per step

    // ---- reduce (redundant per wave): h2[lane], gc[lane] ----
    float sd = ((pd[buf][0][lane] + pd[buf][1][lane]) +
                (pd[buf][2][lane] + pd[buf][3][lane])) + bBd;
    float h2v = fast_tanh(sd);
    float sg = ((pg[buf][0][lane] + pg[buf][1][lane]) +
                (pg[buf][2][lane] + pg[buf][3][lane])) + bBg;
    float gc = fmaxf(sg, 0.f) + __logf(1.f + __expf(-fabsf(sg))) + mind;
    h2c[w][lane] = h2v;
    // intra-wave handoff: no barrier

    // ---- stage C (redundant per wave): 64 MACs, broadcast reads ----
    float d0 = 0.f, d1 = 0.f, d2 = 0.f, d3 = 0.f;
#pragma unroll
    for (int g = 0; g < 16; g++) {
      float4 hv = *(const float4*)&h2c[w][g * 4];
      d0 += hv.x * wC[g * 4 + 0];
      d1 += hv.y * wC[g * 4 + 1];
      d2 += hv.z * wC[g * 4 + 2];
      d3 += hv.w * wC[g * 4 + 3];
    }
    float dc = fminf(fmaxf((d0 + d1) + (d2 + d3) + bC, -maxd), maxd);

    // ---- y update (redundant per wave, own copy) ----
    float yo = ymine;
    float yn = yo + dc * yo * hh + gc * fminf(fmaxf(yo, -10.f), 10.f) * nz * sq;
    yn = fminf(fmaxf(yn, 0.01f), 10.f);
    y_s[w][lane] = yn;
    ymine = yn;
    if (w == 0) out[(long)b * 32768 + (i + 1) * 64 + lane] = yn;
    if (w == 1) outB[((long)b * 512 + i + 1) * 64 + lane] = f2b(yn);
  }
}

// ---------------------------------------------------------------------------
__global__ __launch_bounds__(256) void prep_weights(
    const float* __restrict__ in_W, const float* __restrict__ Wq,
    const float* __restrict__ Wk, const float* __restrict__ Wv,
    const float* __restrict__ Wo, const float* __restrict__ fW1,
    const float* __restrict__ fW2,
    u16* __restrict__ inWt, u16* __restrict__ qkvWt, u16* __restrict__ Wot,
    u16* __restrict__ fW1t, u16* __restrict__ fW2t) {
  const int z = blockIdx.z, layer = blockIdx.y, tile = blockIdx.x;
  const float* src; u16* dst; int R, C, nl;
  switch (z) {
    case 0: src = in_W; dst = inWt; R = 64; C = 128; nl = 1; break;
    case 1: src = Wq + layer * 16384; dst = qkvWt + layer * 49152; R = 128; C = 128; nl = 4; break;
    case 2: src = Wk + layer * 16384; dst = qkvWt + layer * 49152 + 16384; R = 128; C = 128; nl = 4; break;
    case 3: src = Wv + layer * 16384; dst = qkvWt + layer * 49152 + 32768; R = 128; C = 128; nl = 4; break;
    case 4: src = Wo + layer * 16384; dst = Wot + layer * 16384; R = 128; C = 128; nl = 4; break;
    case 5: src = fW1 + layer * 65536; dst = fW1t + layer * 65536; R = 128; C = 512; nl = 4; break;
    default: src = fW2 + layer * 65536; dst = fW2t + layer * 65536; R = 512; C = 128; nl = 4; break;
  }
  const int nt = (R / 32) * (C / 32);
  if (layer >= nl || tile >= nt) return;
  const int tpr = C / 32;
  const int r0 = (tile / tpr) * 32, c0 = (tile % tpr) * 32;
  __shared__ float tl[32][33];
  const int tx = threadIdx.x & 31, ty = threadIdx.x >> 5;
#pragma unroll
  for (int p = 0; p < 4; p++)
    tl[ty + 8 * p][tx] = src[(long)(r0 + ty + 8 * p) * C + c0 + tx];
  __syncthreads();
#pragma unroll
  for (int p = 0; p < 4; p++)
    dst[(long)(c0 + ty + 8 * p) * R + r0 + tx] = f2b(tl[tx][ty + 8 * p]);
}

// ---------------------------------------------------------------------------
// bf16 MFMA GEMM (bf16 out). Used once for x = sde @ in_W.
// ---------------------------------------------------------------------------
__global__ __launch_bounds__(256) void mfma_gemm(
    const u16* __restrict__ A, const u16* __restrict__ Bt,
    const float* __restrict__ bias, u16* __restrict__ outB, int K, int N) {
  __shared__ u16 As[128 * 40];
  __shared__ u16 Bs[64 * 40];
  const int t = threadIdx.x;
  const int nb = blockIdx.x * 64;
  const long mb = (long)blockIdx.y * 128;
  const int lane = t & 63, wave = t >> 6;
  const int wm = (wave >> 1) * 64, wn = (wave & 1) * 32;
  const int fr = lane & 15, quad = lane >> 4;

  f32x4 zero = {0.f, 0.f, 0.f, 0.f};
  f32x4 acc[4][2];
#pragma unroll
  for (int mi = 0; mi < 4; mi++)
#pragma unroll
    for (int ni = 0; ni < 2; ni++) acc[mi][ni] = zero;

  for (int k0 = 0; k0 < K; k0 += 32) {
#pragma unroll
    for (int p = 0; p < 2; p++) {
      int idx = t + p * 256, row = idx >> 2, seg = idx & 3;
      int4 v = *(const int4*)&A[(mb + row) * K + k0 + seg * 8];
      *(int4*)&As[row * 40 + seg * 8] = v;
    }
    {
      int row = t >> 2, seg = t & 3;
      int4 v = *(const int4*)&Bt[(long)(nb + row) * K + k0 + seg * 8];
      *(int4*)&Bs[row * 40 + seg * 8] = v;
    }
    __syncthreads();
    bf16x8 af[4], bfr[2];
#pragma unroll
    for (int mi = 0; mi < 4; mi++)
      af[mi] = *(const bf16x8*)&As[(wm + mi * 16 + fr) * 40 + quad * 8];
#pragma unroll
    for (int ni = 0; ni < 2; ni++)
      bfr[ni] = *(const bf16x8*)&Bs[(wn + ni * 16 + fr) * 40 + quad * 8];
#pragma unroll
    for (int mi = 0; mi < 4; mi++)
#pragma unroll
      for (int ni = 0; ni < 2; ni++)
        acc[mi][ni] = __builtin_amdgcn_mfma_f32_16x16x32_bf16(
            af[mi], bfr[ni], acc[mi][ni], 0, 0, 0);
    __syncthreads();
  }

#pragma unroll
  for (int mi = 0; mi < 4; mi++)
#pragma unroll
    for (int ni = 0; ni < 2; ni++) {
      int col = nb + wn + ni * 16 + fr;
      float bv = bias[col];
#pragma unroll
      for (int r = 0; r < 4; r++) {
        long row = mb + wm + mi * 16 + quad * 4 + r;
        outB[row * N + col] = f2b(acc[mi][ni][r] + bv);
      }
    }
}

// ---------------------------------------------------------------------------
// layer_tail v1b: round-9 v1 + residual prefetch. The LN1 residual reads
// (16 strided u16/thread) were issued at point-of-use between the Wo GEMM
// and the LN1 reduce — fully exposed L2/HBM latency on the serial phase
// chain (1 block/CU). Hoisted to kernel entry: they fly with the ob
// staging loads and drain under staging-barrier + Wo MFMA. +16 VGPR, no
// cap (r1/r10/r11: never cap VGPRs via launch_bounds — spills).
// ---------------------------------------------------------------------------
__global__ __launch_bounds__(512, 1) void layer_tail(
    const u16* __restrict__ ob, const u16* __restrict__ Wot,
    const float* __restrict__ bo, const float* __restrict__ ln1s,
    const float* __restrict__ ln1b, const u16* __restrict__ W1t,
    const float* __restrict__ fb1, const u16* __restrict__ W2t,
    const float* __restrict__ fb2, const float* __restrict__ ln2s,
    const float* __restrict__ ln2b, u16* __restrict__ xb) {
  __shared__ u16 As[64 * 136];        // attn-out tile, then x' tile
  __shared__ u16 Hs[64 * 520];        // hidden tile
  __shared__ float s1[64][8], s2[64][8];
  __shared__ float mst[64][2];
  const int t = threadIdx.x;
  const long mb = (long)blockIdx.x * 64;
  const int w = t >> 6, lane = t & 63;
  const int fr = lane & 15, quad = lane >> 4;
  const int col = w * 16 + fr;        // this thread's output column
  const f32x4 z4 = {0.f, 0.f, 0.f, 0.f};

  // ---- prefetch LN1 residual (latency hides under staging + Wo) ----
  u16 resv[16];
#pragma unroll
  for (int m = 0; m < 4; m++)
#pragma unroll
    for (int r = 0; r < 4; r++)
      resv[m * 4 + r] = xb[(mb + m * 16 + quad * 4 + r) * DD + col];

  // ---- stage attn-out tile 64x128 ----
#pragma unroll
  for (int p = 0; p < 2; p++) {
    int c = t + p * 512;
    int row = c >> 4, sub = c & 15;
    *(int4*)&As[row * 136 + sub * 8] =
        *(const int4*)&ob[(mb + row) * DD + sub * 8];
  }
  __syncthreads();

  // ---- attn-out projection: o @ Wo (K=128), B streamed from L2 ----
  bf16x8 af[4][4];
#pragma unroll
  for (int m = 0; m < 4; m++)
#pragma unroll
    for (int c = 0; c < 4; c++)
      af[m][c] = *(const bf16x8*)&As[(m * 16 + fr) * 136 + c * 32 + quad * 8];

  f32x4 acc[4] = {z4, z4, z4, z4};
#pragma unroll
  for (int kc = 0; kc < 4; kc++) {
    bf16x8 bfr = *(const bf16x8*)&Wot[col * 128 + kc * 32 + quad * 8];
#pragma unroll
    for (int m = 0; m < 4; m++)
      acc[m] = __builtin_amdgcn_mfma_f32_16x16x32_bf16(af[m][kc], bfr,
                                                       acc[m], 0, 0, 0);
  }

  // ---- residual (prefetched) + LN1 partials ----
  const float bov = bo[col], g1 = ln1s[col], be1 = ln1b[col];
  float vv[4][4];
#pragma unroll
  for (int m = 0; m < 4; m++)
#pragma unroll
    for (int r = 0; r < 4; r++) {
      int row = m * 16 + quad * 4 + r;
      float v = acc[m][r] + bov + b2f(resv[m * 4 + r]);
      vv[m][r] = v;
      float s = red16(v);
      float ss = red16(v * v);
      if (fr == 0) { s1[row][w] = s; s2[row][w] = ss; }
    }
  __syncthreads();
  {
    int row = lane;
    float4 a = *(const float4*)&s1[row][0];
    float4 bq4 = *(const float4*)&s1[row][4];
    float sumv = ((a.x + a.y) + (a.z + a.w)) +
                 ((bq4.x + bq4.y) + (bq4.z + bq4.w));
    float4 cq = *(const float4*)&s2[row][0];
    float4 dq = *(const float4*)&s2[row][4];
    float sumsq = ((cq.x + cq.y) + (cq.z + cq.w)) +
                  ((dq.x + dq.y) + (dq.z + dq.w));
    float mean = sumv * (1.f / 128.f);
    float var = sumsq * (1.f / 128.f) - mean * mean;
    mst[row][0] = mean;
    mst[row][1] = rsqrtf(var + 1e-5f);
  }
  __syncthreads();

  // ---- x' = LN1(...): keep in regs (FFN2 residual) + stage in LDS ----
  float xr[4][4];
#pragma unroll
  for (int m = 0; m < 4; m++)
#pragma unroll
    for (int r = 0; r < 4; r++) {
      int row = m * 16 + quad * 4 + r;
      float xv = (vv[m][r] - mst[row][0]) * mst[row][1] * g1 + be1;
      xr[m][r] = xv;
      As[row * 136 + col] = f2b(xv);
    }
  __syncthreads();

  // ---- FFN1: A-frags from x', W1 streamed; wave covers 4 col-tiles ----
  bf16x8 af2[4][4];
#pragma unroll
  for (int m = 0; m < 4; m++)
#pragma unroll
    for (int c = 0; c < 4; c++)
      af2[m][c] = *(const bf16x8*)&As[(m * 16 + fr) * 136 + c * 32 + quad * 8];

#pragma unroll
  for (int nn = 0; nn < 4; nn++) {
    const int nt = w * 4 + nn;
    bf16x8 bfr[4];
#pragma unroll
    for (int c = 0; c < 4; c++)
      bfr[c] = *(const bf16x8*)&W1t[(nt * 16 + fr) * 128 + c * 32 + quad * 8];
    f32x4 a1[4] = {z4, z4, z4, z4};
#pragma unroll
    for (int c = 0; c < 4; c++)
#pragma unroll
      for (int m = 0; m < 4; m++)
        a1[m] = __builtin_amdgcn_mfma_f32_16x16x32_bf16(af2[m][c], bfr[c],
                                                        a1[m], 0, 0, 0);
    const float bv = fb1[nt * 16 + fr];
#pragma unroll
    for (int m = 0; m < 4; m++)
#pragma unroll
      for (int r = 0; r < 4; r++)
        Hs[(m * 16 + quad * 4 + r) * 520 + nt * 16 + fr] =
            f2b(fmaxf(a1[m][r] + bv, 0.f));
  }
  __syncthreads();

  // ---- FFN2: K=512, W2 streamed; wave covers out cols w*16.. ----
  f32x4 acc2[4] = {z4, z4, z4, z4};
#pragma unroll
  for (int kc = 0; kc < 16; kc++) {
    bf16x8 bfr2 = *(const bf16x8*)&W2t[col * 512 + kc * 32 + quad * 8];
    bf16x8 a2[4];
#pragma unroll
    for (int m = 0; m < 4; m++)
      a2[m] = *(const bf16x8*)&Hs[(m * 16 + fr) * 520 + kc * 32 + quad * 8];
#pragma unroll
    for (int m = 0; m < 4; m++)
      acc2[m] = __builtin_amdgcn_mfma_f32_16x16x32_bf16(a2[m], bfr2,
                                                        acc2[m], 0, 0, 0);
  }

  // ---- residual (from regs!) + LN2 ----
  const float bv2 = fb2[col], g2 = ln2s[col], be2 = ln2b[col];
#pragma unroll
  for (int m = 0; m < 4; m++)
#pragma unroll
    for (int r = 0; r < 4; r++) {
      int row = m * 16 + quad * 4 + r;
      float v = acc2[m][r] + bv2 + xr[m][r];
      vv[m][r] = v;
      float s = red16(v);
      float ss = red16(v * v);
      if (fr == 0) { s1[row][w] = s; s2[row][w] = ss; }
    }
  __syncthreads();
  {
    int row = lane;
    float4 a = *(const float4*)&s1[row][0];
    float4 bq4 = *(const float4*)&s1[row][4];
    float sumv = ((a.x + a.y) + (a.z + a.w)) +
                 ((bq4.x + bq4.y) + (bq4.z + bq4.w));
    float4 cq = *(const float4*)&s2[row][0];
    float4 dq = *(const float4*)&s2[row][4];
    float sumsq = ((cq.x + cq.y) + (cq.z + cq.w)) +
                  ((dq.x + dq.y) + (dq.z + dq.w));
    float mean = sumv * (1.f / 128.f);
    float var = sumsq * (1.f / 128.f) - mean * mean;
    mst[row][0] = mean;
    mst[row][1] = rsqrtf(var + 1e-5f);
  }
  __syncthreads();

#pragma unroll
  for (int m = 0; m < 4; m++)
#pragma unroll
    for (int r = 0; r < 4; r++) {
      int row = m * 16 + quad * 4 + r;
      xb[(mb + row) * DD + col] =
          f2b((vv[m][r] - mst[row][0]) * mst[row][1] * g2 + be2);
    }
}

// ---------------------------------------------------------------------------
// Fused QKV-projection + flash attention (round-9 v4, verified champion).
// One block per (b,h), 512 blocks, 2 blocks/CU (64.3 KB LDS).
// V at permuted LDS slots tau(s) = ((s&12)<<1)|(s&3)|((s&16)>>2) so the
// S^T C-layout's native packed words ARE the PV B-frag (no ds_bpermute).
// No-max exp2 softmax (Q pre-scaled by 0.25*log2e), cvt_pk P-packing,
// l-reduction hoisted out of the kt loop. NOTE: v5 (Qs->per-wave scratch +
// launch_bounds(256,3)) regressed +128us — VGPR-cap spills; do not re-try.
// ---------------------------------------------------------------------------
__global__ __launch_bounds__(256, 2) void qkv_attn(
    const u16* __restrict__ xb, const u16* __restrict__ qkvW,
    const float* __restrict__ bq, const float* __restrict__ bk,
    const float* __restrict__ bv, u16* __restrict__ Og) {
  const int bh = blockIdx.x;
  const int b = bh >> 3, h = bh & 7;
  __shared__ u16 Ks[512 * 24];     // [key][d]  (24 KB)
  __shared__ u16 Vt[16 * 520];     // [d][key-slot]  (16.3 KB)
  __shared__ u16 Qs[512 * 24];     // [q][d]    (24 KB)
  const int t = threadIdx.x;
  const int w = t >> 6, lane = t & 63;
  const int fr = lane & 15, quad = lane >> 4;
  const long obase = ((long)b * SS) * DD + h * 16;
  const u16* xrow = xb + (long)b * SS * DD;

  // ---- head weight B-frags (register-resident) ----
  const u16* Wq_h = qkvW + (h * 16) * 128;
  const u16* Wk_h = qkvW + 16384 + (h * 16) * 128;
  const u16* Wv_h = qkvW + 32768 + (h * 16) * 128;
  bf16x8 wqf[4], wkf[4], wvf[4];
#pragma unroll
  for (int c = 0; c < 4; c++) {
    wqf[c] = *(const bf16x8*)&Wq_h[fr * 128 + c * 32 + quad * 8];
    wkf[c] = *(const bf16x8*)&Wk_h[fr * 128 + c * 32 + quad * 8];
    wvf[c] = *(const bf16x8*)&Wv_h[fr * 128 + c * 32 + quad * 8];
  }
  const float bqv = bq[h * 16 + fr];
  const float bkv = bk[h * 16 + fr];
  const float bvv = bv[h * 16 + fr];
  const f32x4 z4 = {0.f, 0.f, 0.f, 0.f};
  const float qscale = 0.25f * 1.4426950408889634f;  // 1/sqrt(16) * log2(e)

  // ---- project Q/K/V for this head into LDS ----
  for (int tile = w; tile < 32; tile += 4) {
    const int t0 = tile * 16;
    bf16x8 af[4];
#pragma unroll
    for (int c = 0; c < 4; c++)
      af[c] = *(const bf16x8*)&xrow[(t0 + fr) * 128 + c * 32 + quad * 8];
    f32x4 qa = z4, ka = z4, va = z4;
#pragma unroll
    for (int c = 0; c < 4; c++) {
      qa = __builtin_amdgcn_mfma_f32_16x16x32_bf16(af[c], wqf[c], qa, 0, 0, 0);
      ka = __builtin_amdgcn_mfma_f32_16x16x32_bf16(af[c], wkf[c], ka, 0, 0, 0);
      va = __builtin_amdgcn_mfma_f32_16x16x32_bf16(af[c], wvf[c], va, 0, 0, 0);
    }
    // C-layout: lane holds (d = fr, row = t0 + quad*4 + r)
#pragma unroll
    for (int r = 0; r < 4; r++) {
      int row = t0 + quad * 4 + r;
      Qs[row * 24 + fr] = f2b((qa[r] + bqv) * qscale);
      Ks[row * 24 + fr] = f2b(ka[r] + bkv);
    }
    // V: permuted slots (tau), 4 consecutive rows -> one b64 write.
    {
      const int t0q = t0 + quad * 4;
      const int r40 = t0q & 31;
      const int vbase = (t0q & ~31) + ((r40 & 12) << 1) + ((r40 & 16) >> 2);
      uint2 vvv;
      vvv.x = cvt_pk_bf16(va[0] + bvv, va[1] + bvv);
      vvv.y = cvt_pk_bf16(va[2] + bvv, va[3] + bvv);
      *(uint2*)&Vt[fr * 520 + vbase] = vvv;
    }
  }
  __syncthreads();

  // ---- flash attention (S^T orientation, no-max exp2 softmax) ----
  for (int qt = w; qt < 32; qt += 4) {
    const int q0 = qt * 16;
    bf16x8 qf = {0, 0, 0, 0, 0, 0, 0, 0};
    if (quad < 2)
      qf = *(const bf16x8*)&Qs[(q0 + fr) * 24 + quad * 8];
    f32x4 oacc = {0.f, 0.f, 0.f, 0.f};
    float rsacc = 0.f;                 // per-lane partial l (reduced once)

    for (int kt = 0; kt < 16; kt++) {
      const int k0 = kt * 32;
      bf16x8 kf0 = {0, 0, 0, 0, 0, 0, 0, 0};
      bf16x8 kf1 = {0, 0, 0, 0, 0, 0, 0, 0};
      if (quad < 2) {
        kf0 = *(const bf16x8*)&Ks[(k0 + fr) * 24 + quad * 8];
        kf1 = *(const bf16x8*)&Ks[(k0 + 16 + fr) * 24 + quad * 8];
      }
      f32x4 slo = __builtin_amdgcn_mfma_f32_16x16x32_bf16(kf0, qf, z4, 0, 0, 0);
      f32x4 shi = __builtin_amdgcn_mfma_f32_16x16x32_bf16(kf1, qf, z4, 0, 0, 0);
      float p[8];
#pragma unroll
      for (int r = 0; r < 4; r++) {
        p[r] = __builtin_amdgcn_exp2f(slo[r]);
        p[4 + r] = __builtin_amdgcn_exp2f(shi[r]);
      }
      rsacc += ((p[0] + p[1]) + (p[2] + p[3])) +
               ((p[4] + p[5]) + (p[6] + p[7]));

      // native packed P words ARE the B-frag (V slots pre-permuted)
      union { unsigned i[4]; bf16x8 v; } pu;
      pu.i[0] = cvt_pk_bf16(p[0], p[1]);
      pu.i[1] = cvt_pk_bf16(p[2], p[3]);
      pu.i[2] = cvt_pk_bf16(p[4], p[5]);
      pu.i[3] = cvt_pk_bf16(p[6], p[7]);
      bf16x8 vf = *(const bf16x8*)&Vt[fr * 520 + k0 + quad * 8];
      oacc = __builtin_amdgcn_mfma_f32_16x16x32_bf16(vf, pu.v, oacc, 0, 0, 0);
    }

    float lrun = rsacc;
    lrun += __shfl_xor(lrun, 16);
    lrun += __shfl_xor(lrun, 32);
    float inv = __fdividef(1.f, lrun);
    uint2 o;
    o.x = cvt_pk_bf16(oacc[0] * inv, oacc[1] * inv);
    o.y = cvt_pk_bf16(oacc[2] * inv, oacc[3] * inv);
    *(uint2*)&Og[obase + (long)(q0 + fr) * DD + quad * 4] = o;
  }
}

// ---------------------------------------------------------------------------
// Fused mean-pool + classifier head (one launch, no bp round-trip).
// ---------------------------------------------------------------------------
__global__ __launch_bounds__(512) void pool_cls(
    const u16* __restrict__ X, const float* __restrict__ W1,
    const float* __restrict__ b1, const float* __restrict__ W2,
    const float* __restrict__ b2, float* __restrict__ L) {
  const int b = blockIdx.x, t = threadIdx.x;
  const int c = t & 127, sg = t >> 7;       // 4 s-groups
  __shared__ float red[4][128];
  __shared__ float sp[128];
  __shared__ float sh[64];
  float acc = 0.f;
  for (int s = sg; s < SS; s += 4)
    acc += b2f(X[((long)b * SS + s) * DD + c]);
  red[sg][c] = acc;
  __syncthreads();
  if (t < 128)
    sp[t] = (red[0][t] + red[1][t] + red[2][t] + red[3][t]) * (1.f / 512.f);
  __syncthreads();
  if (t < 64) {
    float a2 = b1[t];
    for (int k = 0; k < 128; k++) a2 += sp[k] * W1[k * 64 + t];
    sh[t] = fmaxf(a2, 0.f);
  }
  __syncthreads();
  if (t < 5) {
    float a3 = b2[t];
    for (int k = 0; k < 64; k++) a3 += sh[k] * W2[k * 5 + t];
    L[b * 5 + t] = a3;
  }
}

// ---------------------------------------------------------------------------
extern "C" void kernel_launch(void* const* d_in, const int* in_sizes, int n_in,
                              void* d_out, int out_size, void* d_ws, size_t ws_size,
                              hipStream_t stream) {
  const float* ts    = (const float*)d_in[0];
  const float* noise = (const float*)d_in[2];
  const float* dW1   = (const float*)d_in[3];
  const float* db1   = (const float*)d_in[4];
  const float* dW2   = (const float*)d_in[5];
  const float* db2   = (const float*)d_in[6];
  const float* dW3   = (const float*)d_in[7];
  const float* db3   = (const float*)d_in[8];
  const float* gW1   = (const float*)d_in[9];
  const float* gb1   = (const float*)d_in[10];
  const float* gW2   = (const float*)d_in[11];
  const float* gb2   = (const float*)d_in[12];
  const float* mind  = (const float*)d_in[13];
  const float* maxd  = (const float*)d_in[14];
  const float* in_W  = (const float*)d_in[15];
  const float* in_b  = (const float*)d_in[16];
  const float* Wq    = (const float*)d_in[17];
  const float* bq    = (const float*)d_in[18];
  const float* Wk    = (const float*)d_in[19];
  const float* bk    = (const float*)d_in[20];
  const float* Wv    = (const float*)d_in[21];
  const float* bv    = (const float*)d_in[22];
  const float* Wo    = (const float*)d_in[23];
  const float* bo    = (const float*)d_in[24];
  const float* ln1s  = (const float*)d_in[25];
  const float* ln1b  = (const float*)d_in[26];
  const float* fW1   = (const float*)d_in[27];
  const float* fb1   = (const float*)d_in[28];
  const float* fW2   = (const float*)d_in[29];
  const float* fb2   = (const float*)d_in[30];
  const float* ln2s  = (const float*)d_in[31];
  const float* ln2b  = (const float*)d_in[32];
  const float* cW1   = (const float*)d_in[33];
  const float* cb1   = (const float*)d_in[34];
  const float* cW2   = (const float*)d_in[35];
  const float* cb2   = (const float*)d_in[36];

  float* logits = (float*)d_out;
  float* sde    = logits + BB * 5;

  // Workspace (all-bf16 residual stream):
  char* W = (char*)d_ws;
  u16*  bxb    = (u16*)(W);                   //  8 MB bf16 x
  u16*  bob    = (u16*)(W + (40u << 20));     //  8 MB bf16 attn out
  u16*  bsb    = (u16*)(W + (48u << 20));     //  4 MB bf16 sde feats
  u16*  wts    = (u16*)(W + (52u << 20));     // ~1.5 MB bf16 weights

  u16* inWt  = wts;                 // [128][64]
  u16* qkvWt = inWt + 8192;         // [4][3][128][128]
  u16* Wot   = qkvWt + 196608;      // [4][128][128]
  u16* fW1t  = Wot + 65536;         // [4][512][128]
  u16* fW2t  = fW1t + 262144;       // [4][128][512]

  prep_weights<<<dim3(64, 4, 7), 256, 0, stream>>>(in_W, Wq, Wk, Wv, Wo, fW1, fW2,
                                                   inWt, qkvWt, Wot, fW1t, fW2t);

  sde_kernel<<<64, 512, 0, stream>>>(ts, noise, dW1, db1, dW2, db2, dW3, db3,
                                     gW1, gb1, gW2, gb2, mind, maxd, sde, bsb);

  // x = sde @ in_W + in_b  (bf16)
  mfma_gemm<<<dim3(2, 256), 256, 0, stream>>>(bsb, inWt, in_b, bxb, 64, 128);

  for (int l = 0; l < 4; l++) {
    qkv_attn<<<BB * NHD, 256, 0, stream>>>(bxb, qkvWt + l * 49152,
                                           bq + l * DD, bk + l * DD, bv + l * DD,
                                           bob);
    layer_tail<<<512, 512, 0, stream>>>(bob, Wot + l * 16384, bo + l * DD,
                                        ln1s + l * DD, ln1b + l * DD,
                                        fW1t + l * 65536, fb1 + l * 512,
                                        fW2t + l * 65536, fb2 + l * DD,
                                        ln2s + l * DD, ln2b + l * DD, bxb);
  }

  pool_cls<<<BB, 512, 0, stream>>>(bxb, cW1, cb1, cW2, cb2, logits);
}